// Round 2
// baseline (2665.282 us; speedup 1.0000x reference)
//
#include <hip/hip_runtime.h>

#define BB 8
#define NN 4096
#define KK 20
constexpr float EPSV = 1e-5f;
constexpr float SLOPE = 0.2f;

typedef __bf16 bfrag __attribute__((ext_vector_type(8)));
typedef float floatx4 __attribute__((ext_vector_type(4)));
typedef unsigned short us4 __attribute__((ext_vector_type(4)));
typedef unsigned short us8 __attribute__((ext_vector_type(8)));

__device__ __forceinline__ float lrelu(float v) { return v >= 0.f ? v : SLOPE * v; }

__device__ __forceinline__ unsigned short bf16rn(float f) {
    unsigned int u = __float_as_uint(f);
    return (unsigned short)((u + 0x7FFFu + ((u >> 16) & 1u)) >> 16);
}
__device__ __forceinline__ float bf16up(unsigned short h) {
    return __uint_as_float(((unsigned int)h) << 16);
}

__global__ void zero_kernel(float* p, int n) {
    int i = blockIdx.x * 256 + threadIdx.x;
    if (i < n) p[i] = 0.f;
}

// 0.5*||x_n||^2 per point (exact fp32). grid (NN/256, BB), block 256.
template<int C>
__global__ void halfnorm_kernel(const float* __restrict__ src, float* __restrict__ hng) {
    int n = blockIdx.x * 256 + threadIdx.x;
    int b = blockIdx.y;
    float s = 0.f;
    #pragma unroll
    for (int c = 0; c < C; c++) { float v = src[(b * C + c) * NN + n]; s += v * v; }
    hng[b * NN + n] = 0.5f * s;
}

// ---------------- one-shot bf16 hi/lo pack (C>=32) ----------------
// pk[(b*NN+m)*SK + k]: k in [0,C) = hi(c=k); [C,2C) = lo; [2C,SK) = 0 pad.
// Hoists the per-chunk conversion out of knn (was redone 64x per block).
template<int C>
__global__ void pack_kernel(const float* __restrict__ src, unsigned short* __restrict__ pk) {
    constexpr int SK = 2 * C + 8;
    const int b = blockIdx.y;
    const int m0 = blockIdx.x * 64;
    const int tid = threadIdx.x;
    for (int i = tid; i < 64 * (C / 4); i += 256) {
        int m = i & 63;                 // consecutive threads -> consecutive m: coalesced loads
        int c4 = (i >> 6) * 4;
        us4 hv, lv;
        #pragma unroll
        for (int j = 0; j < 4; j++) {
            float v = src[(b * C + c4 + j) * NN + m0 + m];
            unsigned short h = bf16rn(v);
            hv[j] = h;
            lv[j] = bf16rn(v - bf16up(h));
        }
        *(us4*)(&pk[(size_t)(b * NN + m0 + m) * SK + c4]) = hv;
        *(us4*)(&pk[(size_t)(b * NN + m0 + m) * SK + C + c4]) = lv;
    }
    for (int i = tid; i < 64 * 2; i += 256) {
        int m = i >> 1, p = (i & 1) * 4;
        *(us4*)(&pk[(size_t)(b * NN + m0 + m) * SK + 2 * C + p]) = (us4)(0);
    }
}

// ---------------- kNN via MFMA (bf16 hi/lo split, 4-term exact) ----------------
// Score s(q,m) = dot(q,m) - 0.5||x_m||^2 (same top-k set as reference).
// Block 256 (4 waves); tile 64q x 64m per chunk; wave owns 32x32.
// Round-2 restructure:
//  * NO pool / atomics / tau filter. MFMA phase writes the full 64x64 score
//    tile to sv[m][q] (stride 68 -> conflict-free column reads). Drain is a
//    fixed 16-iteration thresholded scan per thread (4 sublanes per q, each
//    keeping a partial top-20; exact: global top20 ∩ partition ⊆ partition
//    top20, merged once at the end). 2 barriers/chunk, uniform trip counts.
//  * C>=32 staging is a pure ushort8 copy from the pre-packed pk buffer,
//    register-prefetched one chunk ahead (no per-chunk conversion VALU).
//  * LDS: C=64 52.5K -> 3 blocks/CU; C=32 36K -> 4 blocks/CU.
template<int C>
__global__ __launch_bounds__(256) void knn_kernel(const float* __restrict__ src,
                                                  const unsigned short* __restrict__ pk,
                                                  const float* __restrict__ hng,
                                                  int* __restrict__ idx) {
    constexpr int SK = (C == 3) ? 40 : (2 * C + 8);   // padded k-stride (shorts)
    constexpr int UNITS = 8 * SK;                     // ushort8 units per 64-row tile
    constexpr int PF = (C == 3) ? 1 : ((UNITS + 255) / 256);
    __shared__ __attribute__((aligned(16))) unsigned short qpack[64 * SK];
    __shared__ __attribute__((aligned(16))) unsigned short cpack[64 * SK];
    __shared__ __attribute__((aligned(16))) float sv[64 * 68];   // [m][q], padded
    __shared__ float hn[64];
    __shared__ unsigned short midx3[(C == 3) ? 64 * 60 : 1];     // merge scratch (C=3)

    const int b = blockIdx.y;
    const int q0 = blockIdx.x * 64;
    const int tid = threadIdx.x;
    const int lane = tid & 63;
    const int wv = tid >> 6;
    const int wr = (wv >> 1) * 32;      // wave q-offset in [0,64)
    const int wc = (wv & 1) * 32;      // wave m-offset in [0,64)
    const int fl = lane & 15;
    const int fq = lane >> 4;
    const int dq = tid & 63;            // drain: q owned by this thread
    const int ds = tid >> 6;            // drain: sublane (m partition, mod 4)

    float tv[20]; int ti[20];
    #pragma unroll
    for (int k = 0; k < 20; k++) { tv[k] = -3.4e38f; ti[k] = 0; }

    us8 pf[PF];
    float pf3[3];
    float hnf = 0.f;

    // ---- stage queries + cpack(chunk 0); prefetch chunk 1 ----
    if (C == 3) {
        for (int i = tid; i < 64 * 20; i += 256) {
            int r = i / 20, k = 12 + i % 20;
            qpack[r * SK + k] = 0; cpack[r * SK + k] = 0;
        }
        if (tid < 64) {
            #pragma unroll
            for (int c = 0; c < 3; c++) {
                float v = src[(b * 3 + c) * NN + q0 + tid];
                unsigned short h = bf16rn(v);
                unsigned short l = bf16rn(v - bf16up(h));
                // A-pack: [h(3) l(3) h(3) l(3)]
                qpack[tid * SK + c] = h;  qpack[tid * SK + 3 + c] = l;
                qpack[tid * SK + 6 + c] = h;  qpack[tid * SK + 9 + c] = l;
                float v2 = src[(b * 3 + c) * NN + tid];            // chunk 0, m = tid
                unsigned short h2 = bf16rn(v2);
                unsigned short l2 = bf16rn(v2 - bf16up(h2));
                // B-pack: [h(3) l(3) l(3) h(3)] -> hh+ll+hl+lh
                cpack[tid * SK + c] = h2;  cpack[tid * SK + 3 + c] = l2;
                cpack[tid * SK + 6 + c] = l2;  cpack[tid * SK + 9 + c] = h2;
            }
            #pragma unroll
            for (int c = 0; c < 3; c++) pf3[c] = src[(b * 3 + c) * NN + 64 + tid];
        }
    } else {
        const unsigned short* pkq = pk + (size_t)(b * NN + q0) * SK;
        const unsigned short* pk0 = pk + (size_t)(b * NN) * SK;
        #pragma unroll
        for (int r = 0; r < PF; r++) {
            int i = r * 256 + tid;
            if (i < UNITS) {
                *(us8*)(qpack + i * 8) = *(const us8*)(pkq + i * 8);
                *(us8*)(cpack + i * 8) = *(const us8*)(pk0 + i * 8);
            }
        }
        const unsigned short* pk1 = pk + (size_t)(b * NN + 64) * SK;
        #pragma unroll
        for (int r = 0; r < PF; r++) {
            int i = r * 256 + tid;
            if (i < UNITS) pf[r] = *(const us8*)(pk1 + i * 8);
        }
    }
    if (tid < 64) {
        hn[tid] = hng[b * NN + tid];
        hnf = hng[b * NN + 64 + tid];
    }
    __syncthreads();

    for (int ch = 0; ch < 64; ch++) {
        // ---- Phase A: MFMA on cpack(ch) -> scores -> sv ----
        floatx4 acc[2][2];
        #pragma unroll
        for (int r2 = 0; r2 < 2; r2++)
            #pragma unroll
            for (int c2 = 0; c2 < 2; c2++)
                acc[r2][c2] = (floatx4)(0.f);

        if (C == 3) {
            #pragma unroll
            for (int r2 = 0; r2 < 2; r2++) {
                bfrag a = *(const bfrag*)(&qpack[(wr + r2 * 16 + fl) * SK + fq * 8]);
                #pragma unroll
                for (int c2 = 0; c2 < 2; c2++) {
                    bfrag bm = *(const bfrag*)(&cpack[(wc + c2 * 16 + fl) * SK + fq * 8]);
                    acc[r2][c2] = __builtin_amdgcn_mfma_f32_16x16x32_bf16(a, bm, acc[r2][c2], 0, 0, 0);
                }
            }
        } else {
            #pragma unroll
            for (int kk = 0; kk < C / 32; kk++) {
                const int kb = kk * 32 + fq * 8;
                bfrag ah[2], al[2], bh[2], bl[2];
                #pragma unroll
                for (int r2 = 0; r2 < 2; r2++) {
                    ah[r2] = *(const bfrag*)(&qpack[(wr + r2 * 16 + fl) * SK + kb]);
                    al[r2] = *(const bfrag*)(&qpack[(wr + r2 * 16 + fl) * SK + C + kb]);
                }
                #pragma unroll
                for (int c2 = 0; c2 < 2; c2++) {
                    bh[c2] = *(const bfrag*)(&cpack[(wc + c2 * 16 + fl) * SK + kb]);
                    bl[c2] = *(const bfrag*)(&cpack[(wc + c2 * 16 + fl) * SK + C + kb]);
                }
                #pragma unroll
                for (int r2 = 0; r2 < 2; r2++)
                    #pragma unroll
                    for (int c2 = 0; c2 < 2; c2++) {
                        acc[r2][c2] = __builtin_amdgcn_mfma_f32_16x16x32_bf16(ah[r2], bh[c2], acc[r2][c2], 0, 0, 0);
                        acc[r2][c2] = __builtin_amdgcn_mfma_f32_16x16x32_bf16(ah[r2], bl[c2], acc[r2][c2], 0, 0, 0);
                        acc[r2][c2] = __builtin_amdgcn_mfma_f32_16x16x32_bf16(al[r2], bh[c2], acc[r2][c2], 0, 0, 0);
                        acc[r2][c2] = __builtin_amdgcn_mfma_f32_16x16x32_bf16(al[r2], bl[c2], acc[r2][c2], 0, 0, 0);
                    }
            }
        }

        // scores: C-layout col=lane&15 (m), row=fq*4+reg (q). sv[m][q] float4 store.
        #pragma unroll
        for (int r2 = 0; r2 < 2; r2++) {
            const int qb = wr + r2 * 16 + fq * 4;
            #pragma unroll
            for (int c2 = 0; c2 < 2; c2++) {
                const int m = wc + c2 * 16 + fl;
                const float h = hn[m];
                float4 s;
                s.x = acc[r2][c2][0] - h;
                s.y = acc[r2][c2][1] - h;
                s.z = acc[r2][c2][2] - h;
                s.w = acc[r2][c2][3] - h;
                *(float4*)(&sv[m * 68 + qb]) = s;
            }
        }
        __syncthreads();

        // ---- Phase B: commit cpack(ch+1) + hn; prefetch ch+2; drain sv(ch) ----
        if (ch + 1 < 64) {
            if (C == 3) {
                if (tid < 64) {
                    #pragma unroll
                    for (int c = 0; c < 3; c++) {
                        float v = pf3[c];
                        unsigned short h = bf16rn(v);
                        unsigned short l = bf16rn(v - bf16up(h));
                        cpack[tid * SK + c] = h;  cpack[tid * SK + 3 + c] = l;
                        cpack[tid * SK + 6 + c] = l;  cpack[tid * SK + 9 + c] = h;
                    }
                }
            } else {
                #pragma unroll
                for (int r = 0; r < PF; r++) {
                    int i = r * 256 + tid;
                    if (i < UNITS) *(us8*)(cpack + i * 8) = pf[r];
                }
            }
            if (tid < 64) hn[tid] = hnf;
        }
        if (ch + 2 < 64) {
            const int m2 = (ch + 2) * 64;
            if (C == 3) {
                if (tid < 64) {
                    #pragma unroll
                    for (int c = 0; c < 3; c++) pf3[c] = src[(b * 3 + c) * NN + m2 + tid];
                }
            } else {
                const unsigned short* pkn = pk + (size_t)(b * NN + m2) * SK;
                #pragma unroll
                for (int r = 0; r < PF; r++) {
                    int i = r * 256 + tid;
                    if (i < UNITS) pf[r] = *(const us8*)(pkn + i * 8);
                }
            }
            if (tid < 64) hnf = hng[b * NN + m2 + tid];
        }
        {
            const int mbase = ch * 64;
            for (int r = 0; r < 16; r++) {
                const int t = ds + r * 4;
                float v = sv[t * 68 + dq];
                if (v > tv[0]) {
                    tv[0] = v; ti[0] = mbase + t;
                    #pragma unroll
                    for (int j = 0; j < 19; j++) {
                        if (tv[j] > tv[j + 1]) {
                            float a = tv[j]; tv[j] = tv[j + 1]; tv[j + 1] = a;
                            int bi = ti[j]; ti[j] = ti[j + 1]; ti[j + 1] = bi;
                        }
                    }
                }
            }
        }
        __syncthreads();
    }

    // ---- merge the 4 partial top-20s into the exact top-20 (once) ----
    unsigned short* midx = (C == 3) ? midx3 : (unsigned short*)qpack;  // qpack dead now
    if (ds > 0) {
        #pragma unroll
        for (int k = 0; k < 20; k++) {
            sv[((ds - 1) * 20 + k) * 68 + dq] = tv[k];
            midx[dq * 60 + (ds - 1) * 20 + k] = (unsigned short)ti[k];
        }
    }
    __syncthreads();
    if (tid < 64) {
        for (int t = 0; t < 60; t++) {
            float v = sv[t * 68 + dq];
            if (v > tv[0]) {
                tv[0] = v; ti[0] = (int)midx[dq * 60 + t];
                #pragma unroll
                for (int j = 0; j < 19; j++) {
                    if (tv[j] > tv[j + 1]) {
                        float a = tv[j]; tv[j] = tv[j + 1]; tv[j + 1] = a;
                        int bi = ti[j]; ti[j] = ti[j + 1]; ti[j + 1] = bi;
                    }
                }
            }
        }
        #pragma unroll
        for (int k = 0; k < 20; k++)
            idx[(b * NN + q0 + dq) * KK + k] = ti[k];   // order irrelevant downstream
    }
}

// ---------------- conv precompute: G = Wd*src, H = (Wc-Wd)*src ----------------
template<int COUT>
__global__ void precompute_kernel(const float* __restrict__ src, int C,
                                  const float* __restrict__ w, int CIN, int wd_off, int wc_off,
                                  float* __restrict__ G, float* __restrict__ H,
                                  int initG, int initH) {
    constexpr int MY = 256 / COUT;
    extern __shared__ float lds[];
    float* wd = lds;
    float* wc = lds + C * COUT;
    const int b = blockIdx.y;
    const int tid = threadIdx.y * COUT + threadIdx.x;
    for (int i = tid; i < C * COUT; i += 256) {
        int c = i / COUT, o = i % COUT;
        float a  = w[o * CIN + wd_off + c];
        float cc = w[o * CIN + wc_off + c];
        wd[i] = a;
        wc[i] = cc - a;
    }
    __syncthreads();
    const int o = threadIdx.x;
    for (int it = 0; it < COUT / 4; it++) {
        int m = blockIdx.x * 64 + it * MY + threadIdx.y;
        float g = 0.f, h = 0.f;
        for (int c = 0; c < C; c++) {
            float s = src[(b * C + c) * NN + m];
            g += wd[c * COUT + o] * s;
            h += wc[c * COUT + o] * s;
        }
        int gi = (b * NN + m) * COUT + o;
        if (initG) G[gi] = g; else G[gi] += g;
        if (initH) H[gi] = h; else H[gi] += h;
    }
}

// ---------------- conv stats + per-(b,n,o) min/max over k ----------------
template<int COUT, int GROUPS>
__global__ void conv_stats_kernel(const float* __restrict__ G1, const int* __restrict__ idx1,
                                  const float* __restrict__ G2, const int* __restrict__ idx2,
                                  const float* __restrict__ H, float* __restrict__ stats,
                                  float* __restrict__ MaxY, float* __restrict__ MinY) {
    constexpr int NY = 256 / COUT;
    const int b = blockIdx.y;
    const int o = threadIdx.x;
    const int n = blockIdx.x * NY + threadIdx.y;
    const int base = b * NN + n;
    const float h = H[base * COUT + o];
    float s1 = 0.f, s2 = 0.f;
    float gx = -3.4e38f, gn = 3.4e38f;
    #pragma unroll
    for (int k = 0; k < KK; k++) {
        int i1 = idx1[base * KK + k];
        float g = G1[(b * NN + i1) * COUT + o];
        if (GROUPS == 2) {
            int i2 = idx2[base * KK + k];
            g += G2[(b * NN + i2) * COUT + o];
        }
        float y = g + h;
        s1 += y;
        s2 += y * y;
        gx = fmaxf(gx, g);
        gn = fminf(gn, g);
    }
    MaxY[base * COUT + o] = gx + h;
    MinY[base * COUT + o] = gn + h;

    __shared__ float ls[2 * COUT];
    if (threadIdx.y == 0) { ls[o] = 0.f; ls[COUT + o] = 0.f; }
    __syncthreads();
    atomicAdd(&ls[o], s1);
    atomicAdd(&ls[COUT + o], s2);
    __syncthreads();
    if (threadIdx.y == 0) {
        atomicAdd(&stats[o], ls[o]);
        atomicAdd(&stats[64 + o], ls[COUT + o]);
    }
}

__global__ void finalize_kernel(const float* __restrict__ g, const float* __restrict__ bb,
                                float* __restrict__ stats, int cout, float invP) {
    int o = threadIdx.x;
    if (o >= cout) return;
    float mu  = stats[o] * invP;
    float var = stats[64 + o] * invP - mu * mu;
    float sc  = g[o] * rsqrtf(var + EPSV);
    stats[128 + o] = sc;
    stats[192 + o] = bb[o] - mu * sc;
}

__global__ void apply_kernel(const float* __restrict__ MaxY, const float* __restrict__ MinY,
                             const float* __restrict__ stats, float* __restrict__ out, int cout) {
    int e = blockIdx.x * 256 + threadIdx.x;
    int total = BB * cout * NN;
    if (e >= total) return;
    int n = e & (NN - 1);
    int o = (e >> 12) % cout;
    int b = e / (NN * cout);
    float sc = stats[128 + o], sh = stats[192 + o];
    int si = (b * NN + n) * cout + o;
    float v = (sc >= 0.f) ? MaxY[si] : MinY[si];
    out[e] = lrelu(sc * v + sh);
}

__global__ void mean_kernel(const float* __restrict__ xd1, const float* __restrict__ xd2,
                            float* __restrict__ hsum) {
    __shared__ float bins[128];
    const int tid = threadIdx.x;
    if (tid < 128) bins[tid] = 0.f;
    __syncthreads();
    const int half = BB * 64 * NN;
    const int stride = gridDim.x * 256;
    for (int e = blockIdx.x * 256 + tid; e < half; e += stride)
        atomicAdd(&bins[e & 127], xd1[e]);
    for (int e = blockIdx.x * 256 + tid; e < half; e += stride)
        atomicAdd(&bins[e & 127], xd2[e]);
    __syncthreads();
    if (tid < 128) atomicAdd(&hsum[tid], bins[tid]);
}

__global__ void head_kernel(const float* __restrict__ hsum,
                            const float* __restrict__ W2d, const float* __restrict__ b2d,
                            const float* __restrict__ W3d, const float* __restrict__ b3d,
                            const float* __restrict__ W4d, const float* __restrict__ b4d,
                            float* __restrict__ out) {
    __shared__ float h[128], t1[128], t2[64];
    const int t = threadIdx.x;
    h[t] = hsum[t] * (1.f / 32768.f);
    __syncthreads();
    float a = b2d[t];
    for (int j = 0; j < 128; j++) a += W2d[t * 128 + j] * h[j];
    t1[t] = lrelu(a);
    __syncthreads();
    if (t < 64) {
        float a2 = b3d[t];
        for (int j = 0; j < 128; j++) a2 += W3d[t * 128 + j] * t1[j];
        t2[t] = lrelu(a2);
    }
    __syncthreads();
    if (t < 11) {
        float a3 = b4d[t];
        for (int j = 0; j < 64; j++) a3 += W4d[t * 64 + j] * t2[j];
        out[t] = lrelu(a3);
    }
}

extern "C" void kernel_launch(void* const* d_in, const int* in_sizes, int n_in,
                              void* d_out, int out_size, void* d_ws, size_t ws_size,
                              hipStream_t stream) {
    const float* x   = (const float*)d_in[0];
    const float* w1  = (const float*)d_in[1];
    const float* g1  = (const float*)d_in[2];
    const float* b1  = (const float*)d_in[3];
    const float* w2  = (const float*)d_in[4];
    const float* g2  = (const float*)d_in[5];
    const float* b2  = (const float*)d_in[6];
    const float* wd1 = (const float*)d_in[7];
    const float* gd1 = (const float*)d_in[8];
    const float* bd1 = (const float*)d_in[9];
    const float* wd2 = (const float*)d_in[10];
    const float* gd2 = (const float*)d_in[11];
    const float* bd2 = (const float*)d_in[12];
    const float* W2d = (const float*)d_in[13];
    const float* b2d = (const float*)d_in[14];
    const float* W3d = (const float*)d_in[15];
    const float* b3d = (const float*)d_in[16];
    const float* W4d = (const float*)d_in[17];
    const float* b4d = (const float*)d_in[18];
    float* out = (float*)d_out;

    char* ws = (char*)d_ws;
    size_t off = 0;
    auto alloc = [&](size_t bytes) { char* p = ws + off; off += (bytes + 255) & ~size_t(255); return p; };
    int*   idx1  = (int*)  alloc(BB * NN * KK * 4);
    int*   idx2  = (int*)  alloc(BB * NN * KK * 4);
    int*   idx3  = (int*)  alloc(BB * NN * KK * 4);
    float* x1m   = (float*)alloc(BB * 32 * NN * 4);
    float* x2m   = (float*)alloc(BB * 64 * NN * 4);
    float* xd1   = (float*)alloc(BB * 64 * NN * 4);
    float* xd2   = (float*)alloc(BB * 64 * NN * 4);
    float* G1    = (float*)alloc((size_t)BB * NN * 64 * 4);
    float* G2    = (float*)alloc((size_t)BB * NN * 64 * 4);
    float* H     = (float*)alloc((size_t)BB * NN * 64 * 4);
    float* MaxY  = (float*)alloc((size_t)BB * NN * 64 * 4);
    float* MinY  = (float*)alloc((size_t)BB * NN * 64 * 4);
    float* stats = (float*)alloc(256 * 4);
    float* hsum  = (float*)alloc(128 * 4);
    float* hng   = (float*)alloc(BB * NN * 4);

    // pk scratch: bf16 hi/lo packed candidates. Reuses MaxY (+ start of MinY for
    // C=64: 8.9MB > 8.4MB) — both are dead at every kNN call site.
    unsigned short* pkbuf = (unsigned short*)MaxY;

    const float invP = 1.f / (float)(BB * NN * KK);
    const dim3 knn_grid(NN / 64, BB);
    const dim3 hn_grid(NN / 256, BB);

    zero_kernel<<<1, 256, 0, stream>>>(hsum, 128);

    // --- kNN on x (C=3): in-kernel conversion (cheap) ---
    halfnorm_kernel<3><<<hn_grid, 256, 0, stream>>>(x, hng);
    knn_kernel<3><<<knn_grid, 256, 0, stream>>>(x, nullptr, hng, idx1);

    // --- conv1: Cout=32, group (x, idx1, C=3), w1 CIN=6 ---
    zero_kernel<<<1, 256, 0, stream>>>(stats, 128);
    precompute_kernel<32><<<dim3(NN / 64, BB), dim3(32, 8), 2 * 3 * 32 * 4, stream>>>(
        x, 3, w1, 6, 0, 3, G1, H, 1, 1);
    conv_stats_kernel<32, 1><<<dim3(NN / 8, BB), dim3(32, 8), 0, stream>>>(
        G1, idx1, nullptr, nullptr, H, stats, MaxY, MinY);
    finalize_kernel<<<1, 64, 0, stream>>>(g1, b1, stats, 32, invP);
    apply_kernel<<<(BB * 32 * NN + 255) / 256, 256, 0, stream>>>(MaxY, MinY, stats, x1m, 32);

    // --- kNN on x1_max (C=32) ---
    pack_kernel<32><<<dim3(NN / 64, BB), 256, 0, stream>>>(x1m, pkbuf);
    halfnorm_kernel<32><<<hn_grid, 256, 0, stream>>>(x1m, hng);
    knn_kernel<32><<<knn_grid, 256, 0, stream>>>(x1m, pkbuf, hng, idx2);

    // --- conv2: Cout=64, groups (x, idx1, 3) + (x1m, idx2, 32), w2 CIN=70 ---
    zero_kernel<<<1, 256, 0, stream>>>(stats, 128);
    precompute_kernel<64><<<dim3(NN / 64, BB), dim3(64, 4), 2 * 3 * 64 * 4, stream>>>(
        x, 3, w2, 70, 0, 3, G1, H, 1, 1);
    precompute_kernel<64><<<dim3(NN / 64, BB), dim3(64, 4), 2 * 32 * 64 * 4, stream>>>(
        x1m, 32, w2, 70, 6, 38, G2, H, 1, 0);
    conv_stats_kernel<64, 2><<<dim3(NN / 4, BB), dim3(64, 4), 0, stream>>>(
        G1, idx1, G2, idx2, H, stats, MaxY, MinY);
    finalize_kernel<<<1, 64, 0, stream>>>(g2, b2, stats, 64, invP);
    apply_kernel<<<(BB * 64 * NN + 255) / 256, 256, 0, stream>>>(MaxY, MinY, stats, x2m, 64);

    // --- convd1: Cout=64, group (x1m, idx2, 32), wd1 CIN=64 ---
    zero_kernel<<<1, 256, 0, stream>>>(stats, 128);
    precompute_kernel<64><<<dim3(NN / 64, BB), dim3(64, 4), 2 * 32 * 64 * 4, stream>>>(
        x1m, 32, wd1, 64, 0, 32, G1, H, 1, 1);
    conv_stats_kernel<64, 1><<<dim3(NN / 4, BB), dim3(64, 4), 0, stream>>>(
        G1, idx2, nullptr, nullptr, H, stats, MaxY, MinY);
    finalize_kernel<<<1, 64, 0, stream>>>(gd1, bd1, stats, 64, invP);
    apply_kernel<<<(BB * 64 * NN + 255) / 256, 256, 0, stream>>>(MaxY, MinY, stats, xd1, 64);

    // --- kNN on x2_max (C=64) ---
    pack_kernel<64><<<dim3(NN / 64, BB), 256, 0, stream>>>(x2m, pkbuf);
    halfnorm_kernel<64><<<hn_grid, 256, 0, stream>>>(x2m, hng);
    knn_kernel<64><<<knn_grid, 256, 0, stream>>>(x2m, pkbuf, hng, idx3);

    // --- convd2: Cout=64, group (x2m, idx3, 64), wd2 CIN=128 ---
    zero_kernel<<<1, 256, 0, stream>>>(stats, 128);
    precompute_kernel<64><<<dim3(NN / 64, BB), dim3(64, 4), 2 * 64 * 64 * 4, stream>>>(
        x2m, 64, wd2, 128, 0, 64, G1, H, 1, 1);
    conv_stats_kernel<64, 1><<<dim3(NN / 4, BB), dim3(64, 4), 0, stream>>>(
        G1, idx3, nullptr, nullptr, H, stats, MaxY, MinY);
    finalize_kernel<<<1, 64, 0, stream>>>(gd2, bd2, stats, 64, invP);
    apply_kernel<<<(BB * 64 * NN + 255) / 256, 256, 0, stream>>>(MaxY, MinY, stats, xd2, 64);

    // --- global mean + MLP head ---
    mean_kernel<<<1024, 256, 0, stream>>>(xd1, xd2, hsum);
    head_kernel<<<1, 128, 0, stream>>>(hsum, W2d, b2d, W3d, b3d, W4d, b4d, out);
}

// Round 3
// 2182.344 us; speedup vs baseline: 1.2213x; 1.2213x over previous
//
#include <hip/hip_runtime.h>

#define BB 8
#define NN 4096
#define KK 20
constexpr float EPSV = 1e-5f;
constexpr float SLOPE = 0.2f;

typedef __bf16 bfrag __attribute__((ext_vector_type(8)));
typedef float floatx4 __attribute__((ext_vector_type(4)));
typedef unsigned short us4 __attribute__((ext_vector_type(4)));
typedef unsigned short us8 __attribute__((ext_vector_type(8)));

__device__ __forceinline__ float lrelu(float v) { return v >= 0.f ? v : SLOPE * v; }

__device__ __forceinline__ unsigned short bf16rn(float f) {
    unsigned int u = __float_as_uint(f);
    return (unsigned short)((u + 0x7FFFu + ((u >> 16) & 1u)) >> 16);
}
__device__ __forceinline__ float bf16up(unsigned short h) {
    return __uint_as_float(((unsigned int)h) << 16);
}

__global__ void zero_kernel(float* p, int n) {
    int i = blockIdx.x * 256 + threadIdx.x;
    if (i < n) p[i] = 0.f;
}

// 0.5*||x_n||^2 per point (exact fp32). grid (NN/256, BB), block 256.
template<int C>
__global__ void halfnorm_kernel(const float* __restrict__ src, float* __restrict__ hng) {
    int n = blockIdx.x * 256 + threadIdx.x;
    int b = blockIdx.y;
    float s = 0.f;
    #pragma unroll
    for (int c = 0; c < C; c++) { float v = src[(b * C + c) * NN + n]; s += v * v; }
    hng[b * NN + n] = 0.5f * s;
}

// ---------------- one-shot bf16 hi/lo pack (C>=32) ----------------
// pk[(b*NN+m)*SK + k]: k in [0,C) = hi; [C,2C) = lo; [2C,SK) = 0 pad.
template<int C>
__global__ void pack_kernel(const float* __restrict__ src, unsigned short* __restrict__ pk) {
    constexpr int SK = 2 * C + 8;
    const int b = blockIdx.y;
    const int m0 = blockIdx.x * 64;
    const int tid = threadIdx.x;
    for (int i = tid; i < 64 * (C / 4); i += 256) {
        int m = i & 63;
        int c4 = (i >> 6) * 4;
        us4 hv, lv;
        #pragma unroll
        for (int j = 0; j < 4; j++) {
            float v = src[(b * C + c4 + j) * NN + m0 + m];
            unsigned short h = bf16rn(v);
            hv[j] = h;
            lv[j] = bf16rn(v - bf16up(h));
        }
        *(us4*)(&pk[(size_t)(b * NN + m0 + m) * SK + c4]) = hv;
        *(us4*)(&pk[(size_t)(b * NN + m0 + m) * SK + C + c4]) = lv;
    }
    for (int i = tid; i < 64 * 2; i += 256) {
        int m = i >> 1, p = (i & 1) * 4;
        *(us4*)(&pk[(size_t)(b * NN + m0 + m) * SK + 2 * C + p]) = (us4)(0);
    }
}

// C=3 B-pack: [h(3) l(3) l(3) h(3) | 0 x28] per point (SK=40) -> hh+ll+hl+lh terms.
__global__ void pack3_kernel(const float* __restrict__ src, unsigned short* __restrict__ pk) {
    const int b = blockIdx.y;
    const int m = blockIdx.x * 256 + threadIdx.x;
    us8 w0, w1;
    #pragma unroll
    for (int j = 0; j < 8; j++) { w0[j] = 0; w1[j] = 0; }
    unsigned short row[12];
    #pragma unroll
    for (int c = 0; c < 3; c++) {
        float v = src[(b * 3 + c) * NN + m];
        unsigned short h = bf16rn(v);
        unsigned short l = bf16rn(v - bf16up(h));
        row[c] = h; row[3 + c] = l; row[6 + c] = l; row[9 + c] = h;
    }
    #pragma unroll
    for (int j = 0; j < 8; j++) w0[j] = row[j];
    #pragma unroll
    for (int j = 0; j < 4; j++) w1[j] = row[8 + j];
    unsigned short* dst = pk + (size_t)(b * NN + m) * 40;
    us8 z;
    #pragma unroll
    for (int j = 0; j < 8; j++) z[j] = 0;
    *(us8*)(dst) = w0;
    *(us8*)(dst + 8) = w1;
    *(us8*)(dst + 16) = z;
    *(us8*)(dst + 24) = z;
    *(us8*)(dst + 32) = z;
}

// ---------------- kNN via MFMA (bf16 hi/lo split, 4-term exact) ----------------
// Round-3: m-split x2 (blockIdx.z = half, 32 chunks each), q-frags in registers,
// extraction-loop drain (argmax + single masked bubble per wave iteration),
// sorted block-partial (val,idx) top-20 written to global; knn_merge finishes.
template<int C>
__global__ __launch_bounds__(256) void knn_kernel(const float* __restrict__ src,
                                                  const unsigned short* __restrict__ pk,
                                                  const float* __restrict__ hng,
                                                  float* __restrict__ pvalg,
                                                  unsigned short* __restrict__ pidxg) {
    constexpr int SK = (C == 3) ? 40 : (2 * C + 8);   // padded k-stride (shorts)
    constexpr int UNITS = 8 * SK;                     // us8 units per 64-row tile
    constexpr int PF = (UNITS + 255) / 256;
    constexpr int NCH = 32;                           // chunks per block (m-split)
    constexpr int SVS = 72;                           // sv row stride (floats)
    constexpr int KKN = (C == 3) ? 1 : (C / 32);
    __shared__ __attribute__((aligned(16))) unsigned short cpack[64 * SK];
    __shared__ __attribute__((aligned(16))) float sv[64 * SVS];   // [m][q]
    __shared__ float hn[64];
    __shared__ unsigned short qls[(C == 3) ? 64 * 40 : 1];        // C=3 A-pack stage
    __shared__ unsigned short midx3[(C == 3) ? 64 * 60 : 1];

    const int b = blockIdx.y;
    const int q0 = blockIdx.x * 64;
    const int half = blockIdx.z;
    const int CH0 = half * NCH;
    const int tid = threadIdx.x;
    const int lane = tid & 63;
    const int wv = tid >> 6;
    const int wr = (wv >> 1) * 32;      // wave q-offset
    const int wc = (wv & 1) * 32;       // wave m-offset
    const int fl = lane & 15;
    const int fq = lane >> 4;
    const int dq = tid & 63;            // drain: owned q
    const int ds = tid >> 6;            // drain: row group (m partition mod 4)

    float tv[20]; int ti[20];
    #pragma unroll
    for (int k = 0; k < 20; k++) { tv[k] = -3.4e38f; ti[k] = 0; }

    // ---- A fragments into registers (once) ----
    bfrag qah[KKN][2], qal[KKN][2];
    if (C == 3) {
        for (int i = tid; i < 64 * 20; i += 256) {
            int r = i / 20, k = 12 + i % 20;
            qls[r * SK + k] = 0;
        }
        if (tid < 64) {
            #pragma unroll
            for (int c = 0; c < 3; c++) {
                float v = src[(b * 3 + c) * NN + q0 + tid];
                unsigned short h = bf16rn(v);
                unsigned short l = bf16rn(v - bf16up(h));
                // A-pack: [h3 l3 h3 l3 | 0...]
                qls[tid * SK + c] = h;  qls[tid * SK + 3 + c] = l;
                qls[tid * SK + 6 + c] = h;  qls[tid * SK + 9 + c] = l;
            }
        }
    } else {
        #pragma unroll
        for (int kk = 0; kk < KKN; kk++)
            #pragma unroll
            for (int r2 = 0; r2 < 2; r2++) {
                const unsigned short* qr = pk + (size_t)(b * NN + q0 + wr + r2 * 16 + fl) * SK + kk * 32 + fq * 8;
                qah[kk][r2] = *(const bfrag*)(qr);
                qal[kk][r2] = *(const bfrag*)(qr + C);
            }
    }

    // ---- stage cpack(chunk CH0); prefetch chunk CH0+1; half-norms ----
    {
        const unsigned short* t0p = pk + (size_t)(b * NN + CH0 * 64) * SK;
        #pragma unroll
        for (int r = 0; r < PF; r++) {
            int i = r * 256 + tid;
            if (i < UNITS) *(us8*)(cpack + i * 8) = *(const us8*)(t0p + i * 8);
        }
    }
    us8 pf[PF];
    {
        const unsigned short* t1p = pk + (size_t)(b * NN + (CH0 + 1) * 64) * SK;
        #pragma unroll
        for (int r = 0; r < PF; r++) {
            int i = r * 256 + tid;
            if (i < UNITS) pf[r] = *(const us8*)(t1p + i * 8);
        }
    }
    float hnf = 0.f;
    if (tid < 64) {
        hn[tid] = hng[b * NN + CH0 * 64 + tid];
        hnf = hng[b * NN + (CH0 + 1) * 64 + tid];
    }
    __syncthreads();

    if (C == 3) {
        #pragma unroll
        for (int r2 = 0; r2 < 2; r2++)
            qah[0][r2] = *(const bfrag*)(&qls[(wr + r2 * 16 + fl) * SK + fq * 8]);
    }

    for (int c = 0; c < NCH; c++) {
        // ---- Phase A: MFMA on cpack(c) -> sv ----
        floatx4 acc[2][2];
        #pragma unroll
        for (int r2 = 0; r2 < 2; r2++)
            #pragma unroll
            for (int c2 = 0; c2 < 2; c2++)
                acc[r2][c2] = (floatx4)(0.f);

        if (C == 3) {
            #pragma unroll
            for (int c2 = 0; c2 < 2; c2++) {
                bfrag bm = *(const bfrag*)(&cpack[(wc + c2 * 16 + fl) * SK + fq * 8]);
                #pragma unroll
                for (int r2 = 0; r2 < 2; r2++)
                    acc[r2][c2] = __builtin_amdgcn_mfma_f32_16x16x32_bf16(qah[0][r2], bm, acc[r2][c2], 0, 0, 0);
            }
        } else {
            #pragma unroll
            for (int kk = 0; kk < KKN; kk++) {
                const int kb = kk * 32 + fq * 8;
                bfrag bh[2], bl[2];
                #pragma unroll
                for (int c2 = 0; c2 < 2; c2++) {
                    bh[c2] = *(const bfrag*)(&cpack[(wc + c2 * 16 + fl) * SK + kb]);
                    bl[c2] = *(const bfrag*)(&cpack[(wc + c2 * 16 + fl) * SK + C + kb]);
                }
                #pragma unroll
                for (int r2 = 0; r2 < 2; r2++)
                    #pragma unroll
                    for (int c2 = 0; c2 < 2; c2++) {
                        acc[r2][c2] = __builtin_amdgcn_mfma_f32_16x16x32_bf16(qah[kk][r2], bh[c2], acc[r2][c2], 0, 0, 0);
                        acc[r2][c2] = __builtin_amdgcn_mfma_f32_16x16x32_bf16(qah[kk][r2], bl[c2], acc[r2][c2], 0, 0, 0);
                        acc[r2][c2] = __builtin_amdgcn_mfma_f32_16x16x32_bf16(qal[kk][r2], bh[c2], acc[r2][c2], 0, 0, 0);
                        acc[r2][c2] = __builtin_amdgcn_mfma_f32_16x16x32_bf16(qal[kk][r2], bl[c2], acc[r2][c2], 0, 0, 0);
                    }
            }
        }

        // C-layout: col=lane&15 (m), row=fq*4+reg (q). sv[m][q] float4 store.
        #pragma unroll
        for (int r2 = 0; r2 < 2; r2++) {
            const int qb = wr + r2 * 16 + fq * 4;
            #pragma unroll
            for (int c2 = 0; c2 < 2; c2++) {
                const int m = wc + c2 * 16 + fl;
                const float h = hn[m];
                float4 s;
                s.x = acc[r2][c2][0] - h;
                s.y = acc[r2][c2][1] - h;
                s.z = acc[r2][c2][2] - h;
                s.w = acc[r2][c2][3] - h;
                *(float4*)(&sv[m * SVS + qb]) = s;
            }
        }
        __syncthreads();

        // ---- Phase B: commit cpack(c+1); prefetch c+2; drain sv(c) ----
        if (c + 1 < NCH) {
            #pragma unroll
            for (int r = 0; r < PF; r++) {
                int i = r * 256 + tid;
                if (i < UNITS) *(us8*)(cpack + i * 8) = pf[r];
            }
            if (tid < 64) hn[tid] = hnf;
        }
        if (c + 2 < NCH) {
            const unsigned short* tn = pk + (size_t)(b * NN + (CH0 + c + 2) * 64) * SK;
            #pragma unroll
            for (int r = 0; r < PF; r++) {
                int i = r * 256 + tid;
                if (i < UNITS) pf[r] = *(const us8*)(tn + i * 8);
            }
            if (tid < 64) hnf = hng[b * NN + (CH0 + c + 2) * 64 + tid];
        }
        {
            const int mbase = (CH0 + c) * 64;
            float v[16];
            #pragma unroll
            for (int r = 0; r < 16; r++) v[r] = sv[(ds + r * 4) * SVS + dq];
            // extraction loop: one masked bubble per wave iteration (not per value)
            while (true) {
                float bm = v[0]; int br = 0;
                #pragma unroll
                for (int r = 1; r < 16; r++) {
                    bool g = v[r] > bm;
                    bm = g ? v[r] : bm;
                    br = g ? r : br;
                }
                bool take = bm > tv[0];
                if (!__any(take ? 1 : 0)) break;
                if (take) {
                    tv[0] = bm; ti[0] = mbase + ds + br * 4;
                    #pragma unroll
                    for (int j = 0; j < 19; j++) {
                        if (tv[j] > tv[j + 1]) {
                            float a = tv[j]; tv[j] = tv[j + 1]; tv[j + 1] = a;
                            int bi = ti[j]; ti[j] = ti[j + 1]; ti[j + 1] = bi;
                        }
                    }
                    #pragma unroll
                    for (int r = 0; r < 16; r++) v[r] = (r == br) ? -3.4e38f : v[r];
                }
            }
        }
        __syncthreads();
    }

    // ---- merge the 4 sublane partial top-20s -> block partial top-20 ----
    unsigned short* midx = (C == 3) ? midx3 : (unsigned short*)cpack;   // cpack dead
    if (ds > 0) {
        #pragma unroll
        for (int k = 0; k < 20; k++) {
            sv[((ds - 1) * 20 + k) * SVS + dq] = tv[k];
            midx[dq * 60 + (ds - 1) * 20 + k] = (unsigned short)ti[k];
        }
    }
    __syncthreads();
    if (tid < 64) {
        for (int t = 0; t < 60; t++) {
            float v = sv[t * SVS + dq];
            if (v > tv[0]) {
                tv[0] = v; ti[0] = (int)midx[dq * 60 + t];
                #pragma unroll
                for (int j = 0; j < 19; j++) {
                    if (tv[j] > tv[j + 1]) {
                        float a = tv[j]; tv[j] = tv[j + 1]; tv[j + 1] = a;
                        int bi = ti[j]; ti[j] = ti[j + 1]; ti[j + 1] = bi;
                    }
                }
            }
        }
        size_t base = ((size_t)(b * NN + q0 + dq) * 2 + half) * 20;
        #pragma unroll
        for (int k = 0; k < 20; k++) {
            pvalg[base + k] = tv[k];                    // ascending
            pidxg[base + k] = (unsigned short)ti[k];
        }
    }
}

// Exact 2-list merge of the per-half sorted top-20s -> final top-20 indices.
__global__ void knn_merge_kernel(const float* __restrict__ pval,
                                 const unsigned short* __restrict__ pidx,
                                 int* __restrict__ idx) {
    int e = blockIdx.x * 256 + threadIdx.x;
    if (e >= BB * NN) return;
    const float* A = pval + (size_t)e * 40;
    const float* B = A + 20;
    const unsigned short* Ai = pidx + (size_t)e * 40;
    const unsigned short* Bi = Ai + 20;
    int ia = 19, ib = 19;
    for (int k = 0; k < 20; k++) {
        float va = A[ia], vb = B[ib];
        bool ta = va >= vb;
        idx[e * KK + k] = ta ? (int)Ai[ia] : (int)Bi[ib];
        ia -= ta ? 1 : 0;
        ib -= ta ? 0 : 1;
    }
}

// ---------------- conv precompute: G = Wd*src, H = (Wc-Wd)*src ----------------
template<int COUT>
__global__ void precompute_kernel(const float* __restrict__ src, int C,
                                  const float* __restrict__ w, int CIN, int wd_off, int wc_off,
                                  float* __restrict__ G, float* __restrict__ H,
                                  int initG, int initH) {
    constexpr int MY = 256 / COUT;
    extern __shared__ float lds[];
    float* wd = lds;
    float* wc = lds + C * COUT;
    const int b = blockIdx.y;
    const int tid = threadIdx.y * COUT + threadIdx.x;
    for (int i = tid; i < C * COUT; i += 256) {
        int c = i / COUT, o = i % COUT;
        float a  = w[o * CIN + wd_off + c];
        float cc = w[o * CIN + wc_off + c];
        wd[i] = a;
        wc[i] = cc - a;
    }
    __syncthreads();
    const int o = threadIdx.x;
    for (int it = 0; it < COUT / 4; it++) {
        int m = blockIdx.x * 64 + it * MY + threadIdx.y;
        float g = 0.f, h = 0.f;
        for (int c = 0; c < C; c++) {
            float s = src[(b * C + c) * NN + m];
            g += wd[c * COUT + o] * s;
            h += wc[c * COUT + o] * s;
        }
        int gi = (b * NN + m) * COUT + o;
        if (initG) G[gi] = g; else G[gi] += g;
        if (initH) H[gi] = h; else H[gi] += h;
    }
}

// ---------------- conv stats + per-(b,n,o) min/max over k ----------------
template<int COUT, int GROUPS>
__global__ void conv_stats_kernel(const float* __restrict__ G1, const int* __restrict__ idx1,
                                  const float* __restrict__ G2, const int* __restrict__ idx2,
                                  const float* __restrict__ H, float* __restrict__ stats,
                                  float* __restrict__ MaxY, float* __restrict__ MinY) {
    constexpr int NY = 256 / COUT;
    const int b = blockIdx.y;
    const int o = threadIdx.x;
    const int n = blockIdx.x * NY + threadIdx.y;
    const int base = b * NN + n;
    const float h = H[base * COUT + o];
    float s1 = 0.f, s2 = 0.f;
    float gx = -3.4e38f, gn = 3.4e38f;
    #pragma unroll
    for (int k = 0; k < KK; k++) {
        int i1 = idx1[base * KK + k];
        float g = G1[(b * NN + i1) * COUT + o];
        if (GROUPS == 2) {
            int i2 = idx2[base * KK + k];
            g += G2[(b * NN + i2) * COUT + o];
        }
        float y = g + h;
        s1 += y;
        s2 += y * y;
        gx = fmaxf(gx, g);
        gn = fminf(gn, g);
    }
    MaxY[base * COUT + o] = gx + h;
    MinY[base * COUT + o] = gn + h;

    __shared__ float ls[2 * COUT];
    if (threadIdx.y == 0) { ls[o] = 0.f; ls[COUT + o] = 0.f; }
    __syncthreads();
    atomicAdd(&ls[o], s1);
    atomicAdd(&ls[COUT + o], s2);
    __syncthreads();
    if (threadIdx.y == 0) {
        atomicAdd(&stats[o], ls[o]);
        atomicAdd(&stats[64 + o], ls[COUT + o]);
    }
}

__global__ void finalize_kernel(const float* __restrict__ g, const float* __restrict__ bb,
                                float* __restrict__ stats, int cout, float invP) {
    int o = threadIdx.x;
    if (o >= cout) return;
    float mu  = stats[o] * invP;
    float var = stats[64 + o] * invP - mu * mu;
    float sc  = g[o] * rsqrtf(var + EPSV);
    stats[128 + o] = sc;
    stats[192 + o] = bb[o] - mu * sc;
}

__global__ void apply_kernel(const float* __restrict__ MaxY, const float* __restrict__ MinY,
                             const float* __restrict__ stats, float* __restrict__ out, int cout) {
    int e = blockIdx.x * 256 + threadIdx.x;
    int total = BB * cout * NN;
    if (e >= total) return;
    int n = e & (NN - 1);
    int o = (e >> 12) % cout;
    int b = e / (NN * cout);
    float sc = stats[128 + o], sh = stats[192 + o];
    int si = (b * NN + n) * cout + o;
    float v = (sc >= 0.f) ? MaxY[si] : MinY[si];
    out[e] = lrelu(sc * v + sh);
}

__global__ void mean_kernel(const float* __restrict__ xd1, const float* __restrict__ xd2,
                            float* __restrict__ hsum) {
    __shared__ float bins[128];
    const int tid = threadIdx.x;
    if (tid < 128) bins[tid] = 0.f;
    __syncthreads();
    const int half = BB * 64 * NN;
    const int stride = gridDim.x * 256;
    for (int e = blockIdx.x * 256 + tid; e < half; e += stride)
        atomicAdd(&bins[e & 127], xd1[e]);
    for (int e = blockIdx.x * 256 + tid; e < half; e += stride)
        atomicAdd(&bins[e & 127], xd2[e]);
    __syncthreads();
    if (tid < 128) atomicAdd(&hsum[tid], bins[tid]);
}

__global__ void head_kernel(const float* __restrict__ hsum,
                            const float* __restrict__ W2d, const float* __restrict__ b2d,
                            const float* __restrict__ W3d, const float* __restrict__ b3d,
                            const float* __restrict__ W4d, const float* __restrict__ b4d,
                            float* __restrict__ out) {
    __shared__ float h[128], t1[128], t2[64];
    const int t = threadIdx.x;
    h[t] = hsum[t] * (1.f / 32768.f);
    __syncthreads();
    float a = b2d[t];
    for (int j = 0; j < 128; j++) a += W2d[t * 128 + j] * h[j];
    t1[t] = lrelu(a);
    __syncthreads();
    if (t < 64) {
        float a2 = b3d[t];
        for (int j = 0; j < 128; j++) a2 += W3d[t * 128 + j] * t1[j];
        t2[t] = lrelu(a2);
    }
    __syncthreads();
    if (t < 11) {
        float a3 = b4d[t];
        for (int j = 0; j < 64; j++) a3 += W4d[t * 64 + j] * t2[j];
        out[t] = lrelu(a3);
    }
}

extern "C" void kernel_launch(void* const* d_in, const int* in_sizes, int n_in,
                              void* d_out, int out_size, void* d_ws, size_t ws_size,
                              hipStream_t stream) {
    const float* x   = (const float*)d_in[0];
    const float* w1  = (const float*)d_in[1];
    const float* g1  = (const float*)d_in[2];
    const float* b1  = (const float*)d_in[3];
    const float* w2  = (const float*)d_in[4];
    const float* g2  = (const float*)d_in[5];
    const float* b2  = (const float*)d_in[6];
    const float* wd1 = (const float*)d_in[7];
    const float* gd1 = (const float*)d_in[8];
    const float* bd1 = (const float*)d_in[9];
    const float* wd2 = (const float*)d_in[10];
    const float* gd2 = (const float*)d_in[11];
    const float* bd2 = (const float*)d_in[12];
    const float* W2d = (const float*)d_in[13];
    const float* b2d = (const float*)d_in[14];
    const float* W3d = (const float*)d_in[15];
    const float* b3d = (const float*)d_in[16];
    const float* W4d = (const float*)d_in[17];
    const float* b4d = (const float*)d_in[18];
    float* out = (float*)d_out;

    char* ws = (char*)d_ws;
    size_t off = 0;
    auto alloc = [&](size_t bytes) { char* p = ws + off; off += (bytes + 255) & ~size_t(255); return p; };
    int*   idx1  = (int*)  alloc(BB * NN * KK * 4);
    int*   idx2  = (int*)  alloc(BB * NN * KK * 4);
    int*   idx3  = (int*)  alloc(BB * NN * KK * 4);
    float* x1m   = (float*)alloc(BB * 32 * NN * 4);
    float* x2m   = (float*)alloc(BB * 64 * NN * 4);
    float* xd1   = (float*)alloc(BB * 64 * NN * 4);
    float* xd2   = (float*)alloc(BB * 64 * NN * 4);
    float* G1    = (float*)alloc((size_t)BB * NN * 64 * 4);
    float* G2    = (float*)alloc((size_t)BB * NN * 64 * 4);
    float* H     = (float*)alloc((size_t)BB * NN * 64 * 4);
    float* MaxY  = (float*)alloc((size_t)BB * NN * 64 * 4);
    float* MinY  = (float*)alloc((size_t)BB * NN * 64 * 4);
    float* stats = (float*)alloc(256 * 4);
    float* hsum  = (float*)alloc(128 * 4);
    float* hng   = (float*)alloc(BB * NN * 4);

    // pk scratch reuses MaxY (+ start of MinY for C=64); dead at every kNN site.
    unsigned short* pkbuf = (unsigned short*)MaxY;
    // knn partials reuse H (pval 5.24MB + pidx 2.62MB <= 8.39MB); dead at kNN sites.
    float* pval = (float*)H;
    unsigned short* pidxp = (unsigned short*)((char*)H + (size_t)BB * NN * 40 * 4);

    const float invP = 1.f / (float)(BB * NN * KK);
    const dim3 knn_grid(NN / 64, BB, 2);
    const dim3 hn_grid(NN / 256, BB);
    const int merge_blocks = (BB * NN + 255) / 256;

    zero_kernel<<<1, 256, 0, stream>>>(hsum, 128);

    // --- kNN on x (C=3) ---
    pack3_kernel<<<dim3(NN / 256, BB), 256, 0, stream>>>(x, pkbuf);
    halfnorm_kernel<3><<<hn_grid, 256, 0, stream>>>(x, hng);
    knn_kernel<3><<<knn_grid, 256, 0, stream>>>(x, pkbuf, hng, pval, pidxp);
    knn_merge_kernel<<<merge_blocks, 256, 0, stream>>>(pval, pidxp, idx1);

    // --- conv1: Cout=32, group (x, idx1, C=3), w1 CIN=6 ---
    zero_kernel<<<1, 256, 0, stream>>>(stats, 128);
    precompute_kernel<32><<<dim3(NN / 64, BB), dim3(32, 8), 2 * 3 * 32 * 4, stream>>>(
        x, 3, w1, 6, 0, 3, G1, H, 1, 1);
    conv_stats_kernel<32, 1><<<dim3(NN / 8, BB), dim3(32, 8), 0, stream>>>(
        G1, idx1, nullptr, nullptr, H, stats, MaxY, MinY);
    finalize_kernel<<<1, 64, 0, stream>>>(g1, b1, stats, 32, invP);
    apply_kernel<<<(BB * 32 * NN + 255) / 256, 256, 0, stream>>>(MaxY, MinY, stats, x1m, 32);

    // --- kNN on x1_max (C=32) ---
    pack_kernel<32><<<dim3(NN / 64, BB), 256, 0, stream>>>(x1m, pkbuf);
    halfnorm_kernel<32><<<hn_grid, 256, 0, stream>>>(x1m, hng);
    knn_kernel<32><<<knn_grid, 256, 0, stream>>>(x1m, pkbuf, hng, pval, pidxp);
    knn_merge_kernel<<<merge_blocks, 256, 0, stream>>>(pval, pidxp, idx2);

    // --- conv2: Cout=64, groups (x, idx1, 3) + (x1m, idx2, 32), w2 CIN=70 ---
    zero_kernel<<<1, 256, 0, stream>>>(stats, 128);
    precompute_kernel<64><<<dim3(NN / 64, BB), dim3(64, 4), 2 * 3 * 64 * 4, stream>>>(
        x, 3, w2, 70, 0, 3, G1, H, 1, 1);
    precompute_kernel<64><<<dim3(NN / 64, BB), dim3(64, 4), 2 * 32 * 64 * 4, stream>>>(
        x1m, 32, w2, 70, 6, 38, G2, H, 1, 0);
    conv_stats_kernel<64, 2><<<dim3(NN / 4, BB), dim3(64, 4), 0, stream>>>(
        G1, idx1, G2, idx2, H, stats, MaxY, MinY);
    finalize_kernel<<<1, 64, 0, stream>>>(g2, b2, stats, 64, invP);
    apply_kernel<<<(BB * 64 * NN + 255) / 256, 256, 0, stream>>>(MaxY, MinY, stats, x2m, 64);

    // --- convd1: Cout=64, group (x1m, idx2, 32), wd1 CIN=64 ---
    zero_kernel<<<1, 256, 0, stream>>>(stats, 128);
    precompute_kernel<64><<<dim3(NN / 64, BB), dim3(64, 4), 2 * 32 * 64 * 4, stream>>>(
        x1m, 32, wd1, 64, 0, 32, G1, H, 1, 1);
    conv_stats_kernel<64, 1><<<dim3(NN / 4, BB), dim3(64, 4), 0, stream>>>(
        G1, idx2, nullptr, nullptr, H, stats, MaxY, MinY);
    finalize_kernel<<<1, 64, 0, stream>>>(gd1, bd1, stats, 64, invP);
    apply_kernel<<<(BB * 64 * NN + 255) / 256, 256, 0, stream>>>(MaxY, MinY, stats, xd1, 64);

    // --- kNN on x2_max (C=64) ---
    pack_kernel<64><<<dim3(NN / 64, BB), 256, 0, stream>>>(x2m, pkbuf);
    halfnorm_kernel<64><<<hn_grid, 256, 0, stream>>>(x2m, hng);
    knn_kernel<64><<<knn_grid, 256, 0, stream>>>(x2m, pkbuf, hng, pval, pidxp);
    knn_merge_kernel<<<merge_blocks, 256, 0, stream>>>(pval, pidxp, idx3);

    // --- convd2: Cout=64, group (x2m, idx3, 64), wd2 CIN=128 ---
    zero_kernel<<<1, 256, 0, stream>>>(stats, 128);
    precompute_kernel<64><<<dim3(NN / 64, BB), dim3(64, 4), 2 * 64 * 64 * 4, stream>>>(
        x2m, 64, wd2, 128, 0, 64, G1, H, 1, 1);
    conv_stats_kernel<64, 1><<<dim3(NN / 4, BB), dim3(64, 4), 0, stream>>>(
        G1, idx3, nullptr, nullptr, H, stats, MaxY, MinY);
    finalize_kernel<<<1, 64, 0, stream>>>(gd2, bd2, stats, 64, invP);
    apply_kernel<<<(BB * 64 * NN + 255) / 256, 256, 0, stream>>>(MaxY, MinY, stats, xd2, 64);

    // --- global mean + MLP head ---
    mean_kernel<<<1024, 256, 0, stream>>>(xd1, xd2, hsum);
    head_kernel<<<1, 128, 0, stream>>>(hsum, W2d, b2d, W3d, b3d, W4d, b4d, out);
}

// Round 5
// 2110.484 us; speedup vs baseline: 1.2629x; 1.0340x over previous
//
#include <hip/hip_runtime.h>

#define BB 8
#define NN 4096
#define KK 20
constexpr float EPSV = 1e-5f;
constexpr float SLOPE = 0.2f;

typedef __bf16 bfrag __attribute__((ext_vector_type(8)));
typedef float floatx4 __attribute__((ext_vector_type(4)));
typedef unsigned short us4 __attribute__((ext_vector_type(4)));
typedef unsigned short us8 __attribute__((ext_vector_type(8)));

__device__ __forceinline__ float lrelu(float v) { return v >= 0.f ? v : SLOPE * v; }

__device__ __forceinline__ unsigned short bf16rn(float f) {
    unsigned int u = __float_as_uint(f);
    return (unsigned short)((u + 0x7FFFu + ((u >> 16) & 1u)) >> 16);
}
__device__ __forceinline__ float bf16up(unsigned short h) {
    return __uint_as_float(((unsigned int)h) << 16);
}

__global__ void zero_kernel(float* p, int n) {
    int i = blockIdx.x * 256 + threadIdx.x;
    if (i < n) p[i] = 0.f;
}

// 0.5*||x_n||^2 per point (exact fp32). grid (NN/256, BB), block 256.
template<int C>
__global__ void halfnorm_kernel(const float* __restrict__ src, float* __restrict__ hng) {
    int n = blockIdx.x * 256 + threadIdx.x;
    int b = blockIdx.y;
    float s = 0.f;
    #pragma unroll
    for (int c = 0; c < C; c++) { float v = src[(b * C + c) * NN + n]; s += v * v; }
    hng[b * NN + n] = 0.5f * s;
}

// ---------------- one-shot bf16 hi/lo pack (C>=32) ----------------
// pk[(b*NN+m)*SK + k]: k in [0,C) = hi; [C,2C) = lo; [2C,SK) = 0 pad.
template<int C>
__global__ void pack_kernel(const float* __restrict__ src, unsigned short* __restrict__ pk) {
    constexpr int SK = 2 * C + 8;
    const int b = blockIdx.y;
    const int m0 = blockIdx.x * 64;
    const int tid = threadIdx.x;
    for (int i = tid; i < 64 * (C / 4); i += 256) {
        int m = i & 63;
        int c4 = (i >> 6) * 4;
        us4 hv, lv;
        #pragma unroll
        for (int j = 0; j < 4; j++) {
            float v = src[(b * C + c4 + j) * NN + m0 + m];
            unsigned short h = bf16rn(v);
            hv[j] = h;
            lv[j] = bf16rn(v - bf16up(h));
        }
        *(us4*)(&pk[(size_t)(b * NN + m0 + m) * SK + c4]) = hv;
        *(us4*)(&pk[(size_t)(b * NN + m0 + m) * SK + C + c4]) = lv;
    }
    for (int i = tid; i < 64 * 2; i += 256) {
        int m = i >> 1, p = (i & 1) * 4;
        *(us4*)(&pk[(size_t)(b * NN + m0 + m) * SK + 2 * C + p]) = (us4)(0);
    }
}

// C=3 B-pack: [h(3) l(3) l(3) h(3) | 0 x28] per point (SK=40) -> hh+ll+hl+lh terms.
__global__ void pack3_kernel(const float* __restrict__ src, unsigned short* __restrict__ pk) {
    const int b = blockIdx.y;
    const int m = blockIdx.x * 256 + threadIdx.x;
    us8 w0, w1;
    #pragma unroll
    for (int j = 0; j < 8; j++) { w0[j] = 0; w1[j] = 0; }
    unsigned short row[12];
    #pragma unroll
    for (int c = 0; c < 3; c++) {
        float v = src[(b * 3 + c) * NN + m];
        unsigned short h = bf16rn(v);
        unsigned short l = bf16rn(v - bf16up(h));
        row[c] = h; row[3 + c] = l; row[6 + c] = l; row[9 + c] = h;
    }
    #pragma unroll
    for (int j = 0; j < 8; j++) w0[j] = row[j];
    #pragma unroll
    for (int j = 0; j < 4; j++) w1[j] = row[8 + j];
    unsigned short* dst = pk + (size_t)(b * NN + m) * 40;
    us8 z;
    #pragma unroll
    for (int j = 0; j < 8; j++) z[j] = 0;
    *(us8*)(dst) = w0;
    *(us8*)(dst + 8) = w1;
    *(us8*)(dst + 16) = z;
    *(us8*)(dst + 24) = z;
    *(us8*)(dst + 32) = z;
}

// ---------------- kNN via MFMA (bf16 hi/lo split, 4-term exact) ----------------
// Round-4: q-split x2 (32 q per block, FULL m-scan -> exact running tau, no merge).
// Pool+atomic filter with exact tau (round-0 statistics: ~126 survivors/q total);
// wave-0 serial drain (lane-parallel over q) OVERLAPPED with waves 1-3 committing
// the prefetched next chunk (pure us8 copy from pre-packed pk; zero conversion
// VALU in-loop). 2 barriers/chunk. LDS ~30.5KB -> 4 blocks/CU (grid 1024).
template<int C>
__global__ __launch_bounds__(256) void knn_kernel(const float* __restrict__ src,
                                                  const unsigned short* __restrict__ pk,
                                                  const float* __restrict__ hng,
                                                  int* __restrict__ idx) {
    constexpr int SK = (C == 3) ? 40 : (2 * C + 8);   // padded k-stride (shorts)
    constexpr int UNITS = 8 * SK;                     // us8 units per 64-row chunk
    constexpr int PFC = (UNITS + 191) / 192;          // commit regs (waves 1-3)
    constexpr int KKN = (C == 3) ? 1 : (C / 32);
    __shared__ __attribute__((aligned(16))) unsigned short cpack[64 * SK];
    __shared__ float pv[32 * 65];
    __shared__ unsigned short pidx[32 * 66];
    __shared__ float hn[64];
    __shared__ float tau[32];
    __shared__ int cnt[32];
    __shared__ unsigned short qls[(C == 3) ? 32 * 40 : 2];

    const int b = blockIdx.y;
    const int q0 = blockIdx.x * 32;
    const int tid = threadIdx.x;
    const int lane = tid & 63;
    const int wv = tid >> 6;
    const int wr = (wv >> 1) * 16;      // wave q-offset in [0,32)
    const int wc = (wv & 1) * 32;       // wave m-offset in [0,64)
    const int fl = lane & 15;
    const int fq = lane >> 4;
    const int ci = tid - 64;            // committer index (waves 1-3): 0..191

    float tv[20]; int ti[20];
    #pragma unroll
    for (int k = 0; k < 20; k++) { tv[k] = -3.4e38f; ti[k] = 0; }

    // ---- A fragments (registers, once) ----
    bfrag qah[KKN], qal[KKN];
    if (C == 3) {
        for (int i = tid; i < 32 * 20; i += 256) {
            int r = i / 20, k = 12 + i % 20;
            qls[r * 40 + k] = 0;
        }
        if (tid < 32) {
            #pragma unroll
            for (int c = 0; c < 3; c++) {
                float v = src[(b * 3 + c) * NN + q0 + tid];
                unsigned short h = bf16rn(v);
                unsigned short l = bf16rn(v - bf16up(h));
                // A-pack: [h3 l3 h3 l3 | 0...] pairs with B-pack [h3 l3 l3 h3]
                qls[tid * 40 + c] = h;  qls[tid * 40 + 3 + c] = l;
                qls[tid * 40 + 6 + c] = h;  qls[tid * 40 + 9 + c] = l;
            }
        }
    } else {
        const unsigned short* qr = pk + (size_t)(b * NN + q0 + wr + fl) * SK + fq * 8;
        #pragma unroll
        for (int kk = 0; kk < KKN; kk++) {
            qah[kk] = *(const bfrag*)(qr + kk * 32);
            qal[kk] = *(const bfrag*)(qr + C + kk * 32);
        }
    }

    // ---- stage chunk 0 (all threads); committers prefetch chunk 1 ----
    {
        const unsigned short* p0 = pk + (size_t)(b * NN) * SK;
        for (int i = tid; i < UNITS; i += 256)
            *(us8*)(cpack + i * 8) = *(const us8*)(p0 + i * 8);
    }
    us8 pf[PFC];
    if (wv > 0) {
        const unsigned short* p1 = pk + (size_t)(b * NN + 64) * SK;
        #pragma unroll
        for (int r = 0; r < PFC; r++) {
            int u = r * 192 + ci;
            if (u < UNITS) pf[r] = *(const us8*)(p1 + u * 8);
        }
    }
    float hnf = 0.f;
    if (wv == 0) {
        hn[lane] = hng[b * NN + lane];
        hnf = hng[b * NN + 64 + lane];
        if (lane < 32) { tau[lane] = -3.4e38f; cnt[lane] = 0; }
    }
    __syncthreads();

    bfrag qa3;
    if (C == 3) qa3 = *(const bfrag*)(&qls[(wr + fl) * 40 + fq * 8]);

    for (int ch = 0; ch < 64; ch++) {
        // ---- Phase A: MFMA on cpack(ch) + filter into pool ----
        floatx4 acc[2];
        acc[0] = (floatx4)(0.f);
        acc[1] = (floatx4)(0.f);

        if (C == 3) {
            #pragma unroll
            for (int c2 = 0; c2 < 2; c2++) {
                bfrag bm = *(const bfrag*)(&cpack[(wc + c2 * 16 + fl) * SK + fq * 8]);
                acc[c2] = __builtin_amdgcn_mfma_f32_16x16x32_bf16(qa3, bm, acc[c2], 0, 0, 0);
            }
        } else {
            #pragma unroll
            for (int kk = 0; kk < KKN; kk++) {
                const int kb = kk * 32 + fq * 8;
                bfrag bh[2], bl[2];
                #pragma unroll
                for (int c2 = 0; c2 < 2; c2++) {
                    bh[c2] = *(const bfrag*)(&cpack[(wc + c2 * 16 + fl) * SK + kb]);
                    bl[c2] = *(const bfrag*)(&cpack[(wc + c2 * 16 + fl) * SK + C + kb]);
                }
                #pragma unroll
                for (int c2 = 0; c2 < 2; c2++) {
                    acc[c2] = __builtin_amdgcn_mfma_f32_16x16x32_bf16(qah[kk], bh[c2], acc[c2], 0, 0, 0);
                    acc[c2] = __builtin_amdgcn_mfma_f32_16x16x32_bf16(qah[kk], bl[c2], acc[c2], 0, 0, 0);
                    acc[c2] = __builtin_amdgcn_mfma_f32_16x16x32_bf16(qal[kk], bh[c2], acc[c2], 0, 0, 0);
                    acc[c2] = __builtin_amdgcn_mfma_f32_16x16x32_bf16(qal[kk], bl[c2], acc[c2], 0, 0, 0);
                }
            }
        }

        // filter: C-layout col=lane&15 (m), row=fq*4+reg (q); exact running tau
        {
            const int m0 = ch * 64;
            const float hnv0 = hn[wc + fl];
            const float hnv1 = hn[wc + 16 + fl];
            float4 t4 = *(const float4*)(&tau[wr + fq * 4]);
            float ta[4] = { t4.x, t4.y, t4.z, t4.w };
            #pragma unroll
            for (int c2 = 0; c2 < 2; c2++) {
                const float hv = c2 ? hnv1 : hnv0;
                const int mm = m0 + wc + c2 * 16 + fl;
                #pragma unroll
                for (int reg = 0; reg < 4; reg++) {
                    float s = acc[c2][reg] - hv;
                    if (s > ta[reg]) {
                        int q = wr + fq * 4 + reg;
                        int p = atomicAdd(&cnt[q], 1);   // <= 64 per chunk: fits
                        pv[q * 65 + p] = s;
                        pidx[q * 66 + p] = (unsigned short)mm;
                    }
                }
            }
        }
        __syncthreads();   // B1: pool complete; cpack(ch) reads done

        // ---- Phase B: wave0 drains (exact top-20 + tau); waves1-3 commit+prefetch ----
        if (wv == 0) {
            if (ch + 1 < 64) hn[lane] = hnf;
            if (ch + 2 < 64) hnf = hng[b * NN + (ch + 2) * 64 + lane];
            if (lane < 32) {
                int n = cnt[lane];
                for (int t = 0; t < n; t++) {
                    float v = pv[lane * 65 + t];
                    if (v > tv[0]) {
                        tv[0] = v; ti[0] = (int)pidx[lane * 66 + t];
                        #pragma unroll
                        for (int j = 0; j < 19; j++) {
                            if (tv[j] > tv[j + 1]) {
                                float a = tv[j]; tv[j] = tv[j + 1]; tv[j + 1] = a;
                                int bi = ti[j]; ti[j] = ti[j + 1]; ti[j + 1] = bi;
                            }
                        }
                    }
                }
                cnt[lane] = 0;
                tau[lane] = tv[0];
            }
        } else {
            if (ch + 1 < 64) {
                #pragma unroll
                for (int r = 0; r < PFC; r++) {
                    int u = r * 192 + ci;
                    if (u < UNITS) *(us8*)(cpack + u * 8) = pf[r];
                }
            }
            if (ch + 2 < 64) {
                const unsigned short* pn = pk + (size_t)(b * NN + (ch + 2) * 64) * SK;
                #pragma unroll
                for (int r = 0; r < PFC; r++) {
                    int u = r * 192 + ci;
                    if (u < UNITS) pf[r] = *(const us8*)(pn + u * 8);
                }
            }
        }
        __syncthreads();   // B2: cpack(ch+1), hn, tau, cnt ready
    }

    if (wv == 0 && lane < 32) {
        #pragma unroll
        for (int k = 0; k < 20; k++)
            idx[(b * NN + q0 + lane) * KK + k] = ti[k];   // order irrelevant downstream
    }
}

// ---------------- conv precompute: G = Wd*src, H = (Wc-Wd)*src ----------------
template<int COUT>
__global__ void precompute_kernel(const float* __restrict__ src, int C,
                                  const float* __restrict__ w, int CIN, int wd_off, int wc_off,
                                  float* __restrict__ G, float* __restrict__ H,
                                  int initG, int initH) {
    constexpr int MY = 256 / COUT;
    extern __shared__ float lds[];
    float* wd = lds;
    float* wc = lds + C * COUT;
    const int b = blockIdx.y;
    const int tid = threadIdx.y * COUT + threadIdx.x;
    for (int i = tid; i < C * COUT; i += 256) {
        int c = i / COUT, o = i % COUT;
        float a  = w[o * CIN + wd_off + c];
        float cc = w[o * CIN + wc_off + c];
        wd[i] = a;
        wc[i] = cc - a;
    }
    __syncthreads();
    const int o = threadIdx.x;
    for (int it = 0; it < COUT / 4; it++) {
        int m = blockIdx.x * 64 + it * MY + threadIdx.y;
        float g = 0.f, h = 0.f;
        for (int c = 0; c < C; c++) {
            float s = src[(b * C + c) * NN + m];
            g += wd[c * COUT + o] * s;
            h += wc[c * COUT + o] * s;
        }
        int gi = (b * NN + m) * COUT + o;
        if (initG) G[gi] = g; else G[gi] += g;
        if (initH) H[gi] = h; else H[gi] += h;
    }
}

// ---------------- conv stats + per-(b,n,o) min/max over k ----------------
template<int COUT, int GROUPS>
__global__ void conv_stats_kernel(const float* __restrict__ G1, const int* __restrict__ idx1,
                                  const float* __restrict__ G2, const int* __restrict__ idx2,
                                  const float* __restrict__ H, float* __restrict__ stats,
                                  float* __restrict__ MaxY, float* __restrict__ MinY) {
    constexpr int NY = 256 / COUT;
    const int b = blockIdx.y;
    const int o = threadIdx.x;
    const int n = blockIdx.x * NY + threadIdx.y;
    const int base = b * NN + n;
    const float h = H[base * COUT + o];
    float s1 = 0.f, s2 = 0.f;
    float gx = -3.4e38f, gn = 3.4e38f;
    #pragma unroll
    for (int k = 0; k < KK; k++) {
        int i1 = idx1[base * KK + k];
        float g = G1[(b * NN + i1) * COUT + o];
        if (GROUPS == 2) {
            int i2 = idx2[base * KK + k];
            g += G2[(b * NN + i2) * COUT + o];
        }
        float y = g + h;
        s1 += y;
        s2 += y * y;
        gx = fmaxf(gx, g);
        gn = fminf(gn, g);
    }
    MaxY[base * COUT + o] = gx + h;
    MinY[base * COUT + o] = gn + h;

    __shared__ float ls[2 * COUT];
    if (threadIdx.y == 0) { ls[o] = 0.f; ls[COUT + o] = 0.f; }
    __syncthreads();
    atomicAdd(&ls[o], s1);
    atomicAdd(&ls[COUT + o], s2);
    __syncthreads();
    if (threadIdx.y == 0) {
        atomicAdd(&stats[o], ls[o]);
        atomicAdd(&stats[64 + o], ls[COUT + o]);
    }
}

__global__ void finalize_kernel(const float* __restrict__ g, const float* __restrict__ bb,
                                float* __restrict__ stats, int cout, float invP) {
    int o = threadIdx.x;
    if (o >= cout) return;
    float mu  = stats[o] * invP;
    float var = stats[64 + o] * invP - mu * mu;
    float sc  = g[o] * rsqrtf(var + EPSV);
    stats[128 + o] = sc;
    stats[192 + o] = bb[o] - mu * sc;
}

__global__ void apply_kernel(const float* __restrict__ MaxY, const float* __restrict__ MinY,
                             const float* __restrict__ stats, float* __restrict__ out, int cout) {
    int e = blockIdx.x * 256 + threadIdx.x;
    int total = BB * cout * NN;
    if (e >= total) return;
    int n = e & (NN - 1);
    int o = (e >> 12) % cout;
    int b = e / (NN * cout);
    float sc = stats[128 + o], sh = stats[192 + o];
    int si = (b * NN + n) * cout + o;
    float v = (sc >= 0.f) ? MaxY[si] : MinY[si];
    out[e] = lrelu(sc * v + sh);
}

__global__ void mean_kernel(const float* __restrict__ xd1, const float* __restrict__ xd2,
                            float* __restrict__ hsum) {
    __shared__ float bins[128];
    const int tid = threadIdx.x;
    if (tid < 128) bins[tid] = 0.f;
    __syncthreads();
    const int half = BB * 64 * NN;
    const int stride = gridDim.x * 256;
    for (int e = blockIdx.x * 256 + tid; e < half; e += stride)
        atomicAdd(&bins[e & 127], xd1[e]);
    for (int e = blockIdx.x * 256 + tid; e < half; e += stride)
        atomicAdd(&bins[e & 127], xd2[e]);
    __syncthreads();
    if (tid < 128) atomicAdd(&hsum[tid], bins[tid]);
}

__global__ void head_kernel(const float* __restrict__ hsum,
                            const float* __restrict__ W2d, const float* __restrict__ b2d,
                            const float* __restrict__ W3d, const float* __restrict__ b3d,
                            const float* __restrict__ W4d, const float* __restrict__ b4d,
                            float* __restrict__ out) {
    __shared__ float h[128], t1[128], t2[64];
    const int t = threadIdx.x;
    h[t] = hsum[t] * (1.f / 32768.f);
    __syncthreads();
    float a = b2d[t];
    for (int j = 0; j < 128; j++) a += W2d[t * 128 + j] * h[j];
    t1[t] = lrelu(a);
    __syncthreads();
    if (t < 64) {
        float a2 = b3d[t];
        for (int j = 0; j < 128; j++) a2 += W3d[t * 128 + j] * t1[j];
        t2[t] = lrelu(a2);
    }
    __syncthreads();
    if (t < 11) {
        float a3 = b4d[t];
        for (int j = 0; j < 64; j++) a3 += W4d[t * 64 + j] * t2[j];
        out[t] = lrelu(a3);
    }
}

extern "C" void kernel_launch(void* const* d_in, const int* in_sizes, int n_in,
                              void* d_out, int out_size, void* d_ws, size_t ws_size,
                              hipStream_t stream) {
    const float* x   = (const float*)d_in[0];
    const float* w1  = (const float*)d_in[1];
    const float* g1  = (const float*)d_in[2];
    const float* b1  = (const float*)d_in[3];
    const float* w2  = (const float*)d_in[4];
    const float* g2  = (const float*)d_in[5];
    const float* b2  = (const float*)d_in[6];
    const float* wd1 = (const float*)d_in[7];
    const float* gd1 = (const float*)d_in[8];
    const float* bd1 = (const float*)d_in[9];
    const float* wd2 = (const float*)d_in[10];
    const float* gd2 = (const float*)d_in[11];
    const float* bd2 = (const float*)d_in[12];
    const float* W2d = (const float*)d_in[13];
    const float* b2d = (const float*)d_in[14];
    const float* W3d = (const float*)d_in[15];
    const float* b3d = (const float*)d_in[16];
    const float* W4d = (const float*)d_in[17];
    const float* b4d = (const float*)d_in[18];
    float* out = (float*)d_out;

    char* ws = (char*)d_ws;
    size_t off = 0;
    auto alloc = [&](size_t bytes) { char* p = ws + off; off += (bytes + 255) & ~size_t(255); return p; };
    int*   idx1  = (int*)  alloc(BB * NN * KK * 4);
    int*   idx2  = (int*)  alloc(BB * NN * KK * 4);
    int*   idx3  = (int*)  alloc(BB * NN * KK * 4);
    float* x1m   = (float*)alloc(BB * 32 * NN * 4);
    float* x2m   = (float*)alloc(BB * 64 * NN * 4);
    float* xd1   = (float*)alloc(BB * 64 * NN * 4);
    float* xd2   = (float*)alloc(BB * 64 * NN * 4);
    float* G1    = (float*)alloc((size_t)BB * NN * 64 * 4);
    float* G2    = (float*)alloc((size_t)BB * NN * 64 * 4);
    float* H     = (float*)alloc((size_t)BB * NN * 64 * 4);
    float* MaxY  = (float*)alloc((size_t)BB * NN * 64 * 4);
    float* MinY  = (float*)alloc((size_t)BB * NN * 64 * 4);
    float* stats = (float*)alloc(256 * 4);
    float* hsum  = (float*)alloc(128 * 4);
    float* hng   = (float*)alloc(BB * NN * 4);

    // pk scratch reuses MaxY (+ start of MinY for C=64); dead at every kNN site.
    unsigned short* pkbuf = (unsigned short*)MaxY;

    const float invP = 1.f / (float)(BB * NN * KK);
    const dim3 knn_grid(NN / 32, BB);      // q-split: 32 q per block, 1024 blocks
    const dim3 hn_grid(NN / 256, BB);

    zero_kernel<<<1, 256, 0, stream>>>(hsum, 128);

    // --- kNN on x (C=3) ---
    pack3_kernel<<<dim3(NN / 256, BB), 256, 0, stream>>>(x, pkbuf);
    halfnorm_kernel<3><<<hn_grid, 256, 0, stream>>>(x, hng);
    knn_kernel<3><<<knn_grid, 256, 0, stream>>>(x, pkbuf, hng, idx1);

    // --- conv1: Cout=32, group (x, idx1, C=3), w1 CIN=6 ---
    zero_kernel<<<1, 256, 0, stream>>>(stats, 128);
    precompute_kernel<32><<<dim3(NN / 64, BB), dim3(32, 8), 2 * 3 * 32 * 4, stream>>>(
        x, 3, w1, 6, 0, 3, G1, H, 1, 1);
    conv_stats_kernel<32, 1><<<dim3(NN / 8, BB), dim3(32, 8), 0, stream>>>(
        G1, idx1, nullptr, nullptr, H, stats, MaxY, MinY);
    finalize_kernel<<<1, 64, 0, stream>>>(g1, b1, stats, 32, invP);
    apply_kernel<<<(BB * 32 * NN + 255) / 256, 256, 0, stream>>>(MaxY, MinY, stats, x1m, 32);

    // --- kNN on x1_max (C=32) ---
    pack_kernel<32><<<dim3(NN / 64, BB), 256, 0, stream>>>(x1m, pkbuf);
    halfnorm_kernel<32><<<hn_grid, 256, 0, stream>>>(x1m, hng);
    knn_kernel<32><<<knn_grid, 256, 0, stream>>>(x1m, pkbuf, hng, idx2);

    // --- conv2: Cout=64, groups (x, idx1, 3) + (x1m, idx2, 32), w2 CIN=70 ---
    zero_kernel<<<1, 256, 0, stream>>>(stats, 128);
    precompute_kernel<64><<<dim3(NN / 64, BB), dim3(64, 4), 2 * 3 * 64 * 4, stream>>>(
        x, 3, w2, 70, 0, 3, G1, H, 1, 1);
    precompute_kernel<64><<<dim3(NN / 64, BB), dim3(64, 4), 2 * 32 * 64 * 4, stream>>>(
        x1m, 32, w2, 70, 6, 38, G2, H, 1, 0);
    conv_stats_kernel<64, 2><<<dim3(NN / 4, BB), dim3(64, 4), 0, stream>>>(
        G1, idx1, G2, idx2, H, stats, MaxY, MinY);
    finalize_kernel<<<1, 64, 0, stream>>>(g2, b2, stats, 64, invP);
    apply_kernel<<<(BB * 64 * NN + 255) / 256, 256, 0, stream>>>(MaxY, MinY, stats, x2m, 64);

    // --- convd1: Cout=64, group (x1m, idx2, 32), wd1 CIN=64 ---
    zero_kernel<<<1, 256, 0, stream>>>(stats, 128);
    precompute_kernel<64><<<dim3(NN / 64, BB), dim3(64, 4), 2 * 32 * 64 * 4, stream>>>(
        x1m, 32, wd1, 64, 0, 32, G1, H, 1, 1);
    conv_stats_kernel<64, 1><<<dim3(NN / 4, BB), dim3(64, 4), 0, stream>>>(
        G1, idx2, nullptr, nullptr, H, stats, MaxY, MinY);
    finalize_kernel<<<1, 64, 0, stream>>>(gd1, bd1, stats, 64, invP);
    apply_kernel<<<(BB * 64 * NN + 255) / 256, 256, 0, stream>>>(MaxY, MinY, stats, xd1, 64);

    // --- kNN on x2_max (C=64) ---
    pack_kernel<64><<<dim3(NN / 64, BB), 256, 0, stream>>>(x2m, pkbuf);
    halfnorm_kernel<64><<<hn_grid, 256, 0, stream>>>(x2m, hng);
    knn_kernel<64><<<knn_grid, 256, 0, stream>>>(x2m, pkbuf, hng, idx3);

    // --- convd2: Cout=64, group (x2m, idx3, 64), wd2 CIN=128 ---
    zero_kernel<<<1, 256, 0, stream>>>(stats, 128);
    precompute_kernel<64><<<dim3(NN / 64, BB), dim3(64, 4), 2 * 64 * 64 * 4, stream>>>(
        x2m, 64, wd2, 128, 0, 64, G1, H, 1, 1);
    conv_stats_kernel<64, 1><<<dim3(NN / 4, BB), dim3(64, 4), 0, stream>>>(
        G1, idx3, nullptr, nullptr, H, stats, MaxY, MinY);
    finalize_kernel<<<1, 64, 0, stream>>>(gd2, bd2, stats, 64, invP);
    apply_kernel<<<(BB * 64 * NN + 255) / 256, 256, 0, stream>>>(MaxY, MinY, stats, xd2, 64);

    // --- global mean + MLP head ---
    mean_kernel<<<1024, 256, 0, stream>>>(xd1, xd2, hsum);
    head_kernel<<<1, 128, 0, stream>>>(hsum, W2d, b2d, W3d, b3d, W4d, b4d, out);
}

// Round 6
// 1755.691 us; speedup vs baseline: 1.5181x; 1.2021x over previous
//
#include <hip/hip_runtime.h>

#define BB 8
#define NN 4096
#define KK 20
constexpr float EPSV = 1e-5f;
constexpr float SLOPE = 0.2f;

typedef __bf16 bfrag __attribute__((ext_vector_type(8)));
typedef float floatx4 __attribute__((ext_vector_type(4)));
typedef unsigned short us4 __attribute__((ext_vector_type(4)));
typedef unsigned short us8 __attribute__((ext_vector_type(8)));

__device__ __forceinline__ float lrelu(float v) { return v >= 0.f ? v : SLOPE * v; }

__device__ __forceinline__ unsigned short bf16rn(float f) {
    unsigned int u = __float_as_uint(f);
    return (unsigned short)((u + 0x7FFFu + ((u >> 16) & 1u)) >> 16);
}
__device__ __forceinline__ float bf16up(unsigned short h) {
    return __uint_as_float(((unsigned int)h) << 16);
}

__global__ void zero_kernel(float* p, int n) {
    int i = blockIdx.x * 256 + threadIdx.x;
    if (i < n) p[i] = 0.f;
}

// 0.5*||x_n||^2 per point (exact fp32). grid (NN/256, BB), block 256.
template<int C>
__global__ void halfnorm_kernel(const float* __restrict__ src, float* __restrict__ hng) {
    int n = blockIdx.x * 256 + threadIdx.x;
    int b = blockIdx.y;
    float s = 0.f;
    #pragma unroll
    for (int c = 0; c < C; c++) { float v = src[(b * C + c) * NN + n]; s += v * v; }
    hng[b * NN + n] = 0.5f * s;
}

// ---------------- one-shot bf16 hi/lo pack (C>=32) ----------------
// pk[(b*NN+m)*SK + k]: k in [0,C) = hi; [C,2C) = lo; [2C,SK) = 0 pad.
template<int C>
__global__ void pack_kernel(const float* __restrict__ src, unsigned short* __restrict__ pk) {
    constexpr int SK = 2 * C + 8;
    const int b = blockIdx.y;
    const int m0 = blockIdx.x * 64;
    const int tid = threadIdx.x;
    for (int i = tid; i < 64 * (C / 4); i += 256) {
        int m = i & 63;
        int c4 = (i >> 6) * 4;
        us4 hv, lv;
        #pragma unroll
        for (int j = 0; j < 4; j++) {
            float v = src[(b * C + c4 + j) * NN + m0 + m];
            unsigned short h = bf16rn(v);
            hv[j] = h;
            lv[j] = bf16rn(v - bf16up(h));
        }
        *(us4*)(&pk[(size_t)(b * NN + m0 + m) * SK + c4]) = hv;
        *(us4*)(&pk[(size_t)(b * NN + m0 + m) * SK + C + c4]) = lv;
    }
    for (int i = tid; i < 64 * 2; i += 256) {
        int m = i >> 1, p = (i & 1) * 4;
        *(us4*)(&pk[(size_t)(b * NN + m0 + m) * SK + 2 * C + p]) = (us4)(0);
    }
}

// C=3 B-pack: [h(3) l(3) l(3) h(3) | 0 x28] per point (SK=40) -> hh+ll+hl+lh terms.
__global__ void pack3_kernel(const float* __restrict__ src, unsigned short* __restrict__ pk) {
    const int b = blockIdx.y;
    const int m = blockIdx.x * 256 + threadIdx.x;
    us8 w0, w1;
    #pragma unroll
    for (int j = 0; j < 8; j++) { w0[j] = 0; w1[j] = 0; }
    unsigned short row[12];
    #pragma unroll
    for (int c = 0; c < 3; c++) {
        float v = src[(b * 3 + c) * NN + m];
        unsigned short h = bf16rn(v);
        unsigned short l = bf16rn(v - bf16up(h));
        row[c] = h; row[3 + c] = l; row[6 + c] = l; row[9 + c] = h;
    }
    #pragma unroll
    for (int j = 0; j < 8; j++) w0[j] = row[j];
    #pragma unroll
    for (int j = 0; j < 4; j++) w1[j] = row[8 + j];
    unsigned short* dst = pk + (size_t)(b * NN + m) * 40;
    us8 z;
    #pragma unroll
    for (int j = 0; j < 8; j++) z[j] = 0;
    *(us8*)(dst) = w0;
    *(us8*)(dst + 8) = w1;
    *(us8*)(dst + 16) = z;
    *(us8*)(dst + 24) = z;
    *(us8*)(dst + 32) = z;
}

// ---------------- kNN via MFMA (bf16 hi/lo split, 4-term exact) ----------------
// Round-6: the measured-305 structure (64 q/block, 3 barriers, exact running tau,
// pool + tid<64 lane-parallel drain) with two proven upgrades:
//  * staging is a pure us8 copy from pre-packed pk (conversion hoisted; rounds 3/5
//    validated correctness). Q-fragments read once from pk into registers.
//  * 1D grid with b = blockIdx.x & 7: all blocks of batch b land on XCD b
//    (wgid%8 round-robin), so the 1.11MB/batch candidate stream is L2-resident.
// LDS ~43KB. Grid 512 blocks (2/CU).
template<int C>
__global__ __launch_bounds__(256) void knn_kernel(const float* __restrict__ src,
                                                  const unsigned short* __restrict__ pk,
                                                  const float* __restrict__ hng,
                                                  int* __restrict__ idx) {
    constexpr int SK = (C == 3) ? 40 : (2 * C + 8);   // padded k-stride (shorts)
    constexpr int UNITS = 8 * SK;                     // us8 units per 64-row chunk
    constexpr int PF = (UNITS + 255) / 256;           // us8 units per thread
    constexpr int KKN = (C == 3) ? 1 : (C / 32);
    __shared__ __attribute__((aligned(16))) unsigned short cpack[64 * SK];
    __shared__ float pv[64 * 65];
    __shared__ unsigned short pidx[64 * 66];
    __shared__ float hn[64];
    __shared__ float tau[64];
    __shared__ int cnt[64];
    __shared__ unsigned short qls[(C == 3) ? 64 * 40 : 2];

    const int bid = blockIdx.x;
    const int b = bid & 7;               // batch -> XCD (wgid % 8 round-robin)
    const int q0 = (bid >> 3) * 64;
    const int tid = threadIdx.x;
    const int lane = tid & 63;
    const int wv = tid >> 6;
    const int wr = (wv >> 1) * 32;      // wave q-offset in [0,64)
    const int wc = (wv & 1) * 32;       // wave m-offset in [0,64)
    const int fl = lane & 15;
    const int fq = lane >> 4;

    float tv[20]; int ti[20];
    #pragma unroll
    for (int k = 0; k < 20; k++) { tv[k] = -3.4e38f; ti[k] = 0; }

    // ---- A fragments (registers, once) ----
    bfrag qah[KKN][2], qal[KKN][2];
    if (C == 3) {
        for (int i = tid; i < 64 * 20; i += 256) {
            int r = i / 20, k = 12 + i % 20;
            qls[r * 40 + k] = 0;
        }
        if (tid < 64) {
            #pragma unroll
            for (int c = 0; c < 3; c++) {
                float v = src[(b * 3 + c) * NN + q0 + tid];
                unsigned short h = bf16rn(v);
                unsigned short l = bf16rn(v - bf16up(h));
                // A-pack: [h3 l3 h3 l3 | 0...] pairs with B-pack [h3 l3 l3 h3]
                qls[tid * 40 + c] = h;  qls[tid * 40 + 3 + c] = l;
                qls[tid * 40 + 6 + c] = h;  qls[tid * 40 + 9 + c] = l;
            }
        }
    } else {
        #pragma unroll
        for (int r2 = 0; r2 < 2; r2++) {
            const unsigned short* qr = pk + (size_t)(b * NN + q0 + wr + r2 * 16 + fl) * SK + fq * 8;
            #pragma unroll
            for (int kk = 0; kk < KKN; kk++) {
                qah[kk][r2] = *(const bfrag*)(qr + kk * 32);
                qal[kk][r2] = *(const bfrag*)(qr + C + kk * 32);
            }
        }
    }

    // ---- stage chunk 0; prefetch chunk 1; half-norms ----
    {
        const unsigned short* p0 = pk + (size_t)(b * NN) * SK;
        #pragma unroll
        for (int r = 0; r < PF; r++) {
            int u = r * 256 + tid;
            if (u < UNITS) *(us8*)(cpack + u * 8) = *(const us8*)(p0 + u * 8);
        }
    }
    us8 pf[PF];
    {
        const unsigned short* p1 = pk + (size_t)(b * NN + 64) * SK;
        #pragma unroll
        for (int r = 0; r < PF; r++) {
            int u = r * 256 + tid;
            if (u < UNITS) pf[r] = *(const us8*)(p1 + u * 8);
        }
    }
    float hnf = 0.f;
    if (tid < 64) {
        hn[tid] = hng[b * NN + tid];
        hnf = hng[b * NN + 64 + tid];
        tau[tid] = -3.4e38f;
        cnt[tid] = 0;
    }
    __syncthreads();

    bfrag qa3[2];
    if (C == 3) {
        #pragma unroll
        for (int r2 = 0; r2 < 2; r2++)
            qa3[r2] = *(const bfrag*)(&qls[(wr + r2 * 16 + fl) * 40 + fq * 8]);
    }

    for (int ch = 0; ch < 64; ch++) {
        // ---- Phase S: commit prefetched chunk; issue prefetch ch+1 ----
        if (ch > 0) {
            #pragma unroll
            for (int r = 0; r < PF; r++) {
                int u = r * 256 + tid;
                if (u < UNITS) *(us8*)(cpack + u * 8) = pf[r];
            }
            if (tid < 64) hn[tid] = hnf;
        }
        if (ch + 1 < 64) {
            const unsigned short* pn = pk + (size_t)(b * NN + (ch + 1) * 64) * SK;
            #pragma unroll
            for (int r = 0; r < PF; r++) {
                int u = r * 256 + tid;
                if (u < UNITS) pf[r] = *(const us8*)(pn + u * 8);
            }
            if (tid < 64) hnf = hng[b * NN + (ch + 1) * 64 + tid];
        }
        __syncthreads();

        // ---- MFMA on cpack(ch) ----
        floatx4 acc[2][2];
        #pragma unroll
        for (int r2 = 0; r2 < 2; r2++)
            #pragma unroll
            for (int c2 = 0; c2 < 2; c2++)
                acc[r2][c2] = (floatx4)(0.f);

        if (C == 3) {
            #pragma unroll
            for (int c2 = 0; c2 < 2; c2++) {
                bfrag bm = *(const bfrag*)(&cpack[(wc + c2 * 16 + fl) * SK + fq * 8]);
                #pragma unroll
                for (int r2 = 0; r2 < 2; r2++)
                    acc[r2][c2] = __builtin_amdgcn_mfma_f32_16x16x32_bf16(qa3[r2], bm, acc[r2][c2], 0, 0, 0);
            }
        } else {
            #pragma unroll
            for (int kk = 0; kk < KKN; kk++) {
                const int kb = kk * 32 + fq * 8;
                bfrag bh[2], bl[2];
                #pragma unroll
                for (int c2 = 0; c2 < 2; c2++) {
                    bh[c2] = *(const bfrag*)(&cpack[(wc + c2 * 16 + fl) * SK + kb]);
                    bl[c2] = *(const bfrag*)(&cpack[(wc + c2 * 16 + fl) * SK + C + kb]);
                }
                #pragma unroll
                for (int r2 = 0; r2 < 2; r2++)
                    #pragma unroll
                    for (int c2 = 0; c2 < 2; c2++) {
                        acc[r2][c2] = __builtin_amdgcn_mfma_f32_16x16x32_bf16(qah[kk][r2], bh[c2], acc[r2][c2], 0, 0, 0);
                        acc[r2][c2] = __builtin_amdgcn_mfma_f32_16x16x32_bf16(qah[kk][r2], bl[c2], acc[r2][c2], 0, 0, 0);
                        acc[r2][c2] = __builtin_amdgcn_mfma_f32_16x16x32_bf16(qal[kk][r2], bh[c2], acc[r2][c2], 0, 0, 0);
                        acc[r2][c2] = __builtin_amdgcn_mfma_f32_16x16x32_bf16(qal[kk][r2], bl[c2], acc[r2][c2], 0, 0, 0);
                    }
            }
        }

        // ---- filter: C-layout col=lane&15 (m), row=fq*4+reg (q); exact tau ----
        {
            const int m0 = ch * 64;
            const float hnv0 = hn[wc + fl];
            const float hnv1 = hn[wc + 16 + fl];
            #pragma unroll
            for (int r2 = 0; r2 < 2; r2++) {
                const int qb = wr + r2 * 16 + fq * 4;
                float4 t4 = *(const float4*)(&tau[qb]);
                float ta[4] = { t4.x, t4.y, t4.z, t4.w };
                #pragma unroll
                for (int c2 = 0; c2 < 2; c2++) {
                    const float hv = c2 ? hnv1 : hnv0;
                    const int mm = m0 + wc + c2 * 16 + fl;
                    #pragma unroll
                    for (int reg = 0; reg < 4; reg++) {
                        float s = acc[r2][c2][reg] - hv;
                        if (s > ta[reg]) {
                            int q = qb + reg;
                            int p = atomicAdd(&cnt[q], 1);   // <= 64 per chunk: fits
                            pv[q * 65 + p] = s;
                            pidx[q * 66 + p] = (unsigned short)mm;
                        }
                    }
                }
            }
        }
        __syncthreads();

        // ---- drain: tid<64, lane-parallel over q; exact top-20 + tau ----
        if (tid < 64) {
            int n = cnt[tid];
            for (int t = 0; t < n; t++) {
                float v = pv[tid * 65 + t];
                if (v > tv[0]) {
                    tv[0] = v; ti[0] = (int)pidx[tid * 66 + t];
                    #pragma unroll
                    for (int j = 0; j < 19; j++) {
                        if (tv[j] > tv[j + 1]) {
                            float a = tv[j]; tv[j] = tv[j + 1]; tv[j + 1] = a;
                            int bi = ti[j]; ti[j] = ti[j + 1]; ti[j + 1] = bi;
                        }
                    }
                }
            }
            cnt[tid] = 0;
            tau[tid] = tv[0];
        }
        __syncthreads();
    }

    if (tid < 64) {
        #pragma unroll
        for (int k = 0; k < 20; k++)
            idx[(b * NN + q0 + tid) * KK + k] = ti[k];   // order irrelevant downstream
    }
}

// ---------------- conv precompute: G = Wd*src, H = (Wc-Wd)*src ----------------
template<int COUT>
__global__ void precompute_kernel(const float* __restrict__ src, int C,
                                  const float* __restrict__ w, int CIN, int wd_off, int wc_off,
                                  float* __restrict__ G, float* __restrict__ H,
                                  int initG, int initH) {
    constexpr int MY = 256 / COUT;
    extern __shared__ float lds[];
    float* wd = lds;
    float* wc = lds + C * COUT;
    const int b = blockIdx.y;
    const int tid = threadIdx.y * COUT + threadIdx.x;
    for (int i = tid; i < C * COUT; i += 256) {
        int c = i / COUT, o = i % COUT;
        float a  = w[o * CIN + wd_off + c];
        float cc = w[o * CIN + wc_off + c];
        wd[i] = a;
        wc[i] = cc - a;
    }
    __syncthreads();
    const int o = threadIdx.x;
    for (int it = 0; it < COUT / 4; it++) {
        int m = blockIdx.x * 64 + it * MY + threadIdx.y;
        float g = 0.f, h = 0.f;
        for (int c = 0; c < C; c++) {
            float s = src[(b * C + c) * NN + m];
            g += wd[c * COUT + o] * s;
            h += wc[c * COUT + o] * s;
        }
        int gi = (b * NN + m) * COUT + o;
        if (initG) G[gi] = g; else G[gi] += g;
        if (initH) H[gi] = h; else H[gi] += h;
    }
}

// ---------------- conv stats + per-(b,n,o) min/max over k ----------------
template<int COUT, int GROUPS>
__global__ void conv_stats_kernel(const float* __restrict__ G1, const int* __restrict__ idx1,
                                  const float* __restrict__ G2, const int* __restrict__ idx2,
                                  const float* __restrict__ H, float* __restrict__ stats,
                                  float* __restrict__ MaxY, float* __restrict__ MinY) {
    constexpr int NY = 256 / COUT;
    const int b = blockIdx.y;
    const int o = threadIdx.x;
    const int n = blockIdx.x * NY + threadIdx.y;
    const int base = b * NN + n;
    const float h = H[base * COUT + o];
    float s1 = 0.f, s2 = 0.f;
    float gx = -3.4e38f, gn = 3.4e38f;
    #pragma unroll
    for (int k = 0; k < KK; k++) {
        int i1 = idx1[base * KK + k];
        float g = G1[(b * NN + i1) * COUT + o];
        if (GROUPS == 2) {
            int i2 = idx2[base * KK + k];
            g += G2[(b * NN + i2) * COUT + o];
        }
        float y = g + h;
        s1 += y;
        s2 += y * y;
        gx = fmaxf(gx, g);
        gn = fminf(gn, g);
    }
    MaxY[base * COUT + o] = gx + h;
    MinY[base * COUT + o] = gn + h;

    __shared__ float ls[2 * COUT];
    if (threadIdx.y == 0) { ls[o] = 0.f; ls[COUT + o] = 0.f; }
    __syncthreads();
    atomicAdd(&ls[o], s1);
    atomicAdd(&ls[COUT + o], s2);
    __syncthreads();
    if (threadIdx.y == 0) {
        atomicAdd(&stats[o], ls[o]);
        atomicAdd(&stats[64 + o], ls[COUT + o]);
    }
}

__global__ void finalize_kernel(const float* __restrict__ g, const float* __restrict__ bb,
                                float* __restrict__ stats, int cout, float invP) {
    int o = threadIdx.x;
    if (o >= cout) return;
    float mu  = stats[o] * invP;
    float var = stats[64 + o] * invP - mu * mu;
    float sc  = g[o] * rsqrtf(var + EPSV);
    stats[128 + o] = sc;
    stats[192 + o] = bb[o] - mu * sc;
}

__global__ void apply_kernel(const float* __restrict__ MaxY, const float* __restrict__ MinY,
                             const float* __restrict__ stats, float* __restrict__ out, int cout) {
    int e = blockIdx.x * 256 + threadIdx.x;
    int total = BB * cout * NN;
    if (e >= total) return;
    int n = e & (NN - 1);
    int o = (e >> 12) % cout;
    int b = e / (NN * cout);
    float sc = stats[128 + o], sh = stats[192 + o];
    int si = (b * NN + n) * cout + o;
    float v = (sc >= 0.f) ? MaxY[si] : MinY[si];
    out[e] = lrelu(sc * v + sh);
}

__global__ void mean_kernel(const float* __restrict__ xd1, const float* __restrict__ xd2,
                            float* __restrict__ hsum) {
    __shared__ float bins[128];
    const int tid = threadIdx.x;
    if (tid < 128) bins[tid] = 0.f;
    __syncthreads();
    const int half = BB * 64 * NN;
    const int stride = gridDim.x * 256;
    for (int e = blockIdx.x * 256 + tid; e < half; e += stride)
        atomicAdd(&bins[e & 127], xd1[e]);
    for (int e = blockIdx.x * 256 + tid; e < half; e += stride)
        atomicAdd(&bins[e & 127], xd2[e]);
    __syncthreads();
    if (tid < 128) atomicAdd(&hsum[tid], bins[tid]);
}

__global__ void head_kernel(const float* __restrict__ hsum,
                            const float* __restrict__ W2d, const float* __restrict__ b2d,
                            const float* __restrict__ W3d, const float* __restrict__ b3d,
                            const float* __restrict__ W4d, const float* __restrict__ b4d,
                            float* __restrict__ out) {
    __shared__ float h[128], t1[128], t2[64];
    const int t = threadIdx.x;
    h[t] = hsum[t] * (1.f / 32768.f);
    __syncthreads();
    float a = b2d[t];
    for (int j = 0; j < 128; j++) a += W2d[t * 128 + j] * h[j];
    t1[t] = lrelu(a);
    __syncthreads();
    if (t < 64) {
        float a2 = b3d[t];
        for (int j = 0; j < 128; j++) a2 += W3d[t * 128 + j] * t1[j];
        t2[t] = lrelu(a2);
    }
    __syncthreads();
    if (t < 11) {
        float a3 = b4d[t];
        for (int j = 0; j < 64; j++) a3 += W4d[t * 64 + j] * t2[j];
        out[t] = lrelu(a3);
    }
}

extern "C" void kernel_launch(void* const* d_in, const int* in_sizes, int n_in,
                              void* d_out, int out_size, void* d_ws, size_t ws_size,
                              hipStream_t stream) {
    const float* x   = (const float*)d_in[0];
    const float* w1  = (const float*)d_in[1];
    const float* g1  = (const float*)d_in[2];
    const float* b1  = (const float*)d_in[3];
    const float* w2  = (const float*)d_in[4];
    const float* g2  = (const float*)d_in[5];
    const float* b2  = (const float*)d_in[6];
    const float* wd1 = (const float*)d_in[7];
    const float* gd1 = (const float*)d_in[8];
    const float* bd1 = (const float*)d_in[9];
    const float* wd2 = (const float*)d_in[10];
    const float* gd2 = (const float*)d_in[11];
    const float* bd2 = (const float*)d_in[12];
    const float* W2d = (const float*)d_in[13];
    const float* b2d = (const float*)d_in[14];
    const float* W3d = (const float*)d_in[15];
    const float* b3d = (const float*)d_in[16];
    const float* W4d = (const float*)d_in[17];
    const float* b4d = (const float*)d_in[18];
    float* out = (float*)d_out;

    char* ws = (char*)d_ws;
    size_t off = 0;
    auto alloc = [&](size_t bytes) { char* p = ws + off; off += (bytes + 255) & ~size_t(255); return p; };
    int*   idx1  = (int*)  alloc(BB * NN * KK * 4);
    int*   idx2  = (int*)  alloc(BB * NN * KK * 4);
    int*   idx3  = (int*)  alloc(BB * NN * KK * 4);
    float* x1m   = (float*)alloc(BB * 32 * NN * 4);
    float* x2m   = (float*)alloc(BB * 64 * NN * 4);
    float* xd1   = (float*)alloc(BB * 64 * NN * 4);
    float* xd2   = (float*)alloc(BB * 64 * NN * 4);
    float* G1    = (float*)alloc((size_t)BB * NN * 64 * 4);
    float* G2    = (float*)alloc((size_t)BB * NN * 64 * 4);
    float* H     = (float*)alloc((size_t)BB * NN * 64 * 4);
    float* MaxY  = (float*)alloc((size_t)BB * NN * 64 * 4);
    float* MinY  = (float*)alloc((size_t)BB * NN * 64 * 4);
    float* stats = (float*)alloc(256 * 4);
    float* hsum  = (float*)alloc(128 * 4);
    float* hng   = (float*)alloc(BB * NN * 4);

    // pk scratch reuses MaxY (+ start of MinY for C=64); dead at every kNN site.
    unsigned short* pkbuf = (unsigned short*)MaxY;

    const float invP = 1.f / (float)(BB * NN * KK);
    const dim3 knn_grid(NN / 64 * BB);     // 1D: b = id & 7 (XCD pinning), q0 = (id>>3)*64
    const dim3 hn_grid(NN / 256, BB);

    zero_kernel<<<1, 256, 0, stream>>>(hsum, 128);

    // --- kNN on x (C=3) ---
    pack3_kernel<<<dim3(NN / 256, BB), 256, 0, stream>>>(x, pkbuf);
    halfnorm_kernel<3><<<hn_grid, 256, 0, stream>>>(x, hng);
    knn_kernel<3><<<knn_grid, 256, 0, stream>>>(x, pkbuf, hng, idx1);

    // --- conv1: Cout=32, group (x, idx1, C=3), w1 CIN=6 ---
    zero_kernel<<<1, 256, 0, stream>>>(stats, 128);
    precompute_kernel<32><<<dim3(NN / 64, BB), dim3(32, 8), 2 * 3 * 32 * 4, stream>>>(
        x, 3, w1, 6, 0, 3, G1, H, 1, 1);
    conv_stats_kernel<32, 1><<<dim3(NN / 8, BB), dim3(32, 8), 0, stream>>>(
        G1, idx1, nullptr, nullptr, H, stats, MaxY, MinY);
    finalize_kernel<<<1, 64, 0, stream>>>(g1, b1, stats, 32, invP);
    apply_kernel<<<(BB * 32 * NN + 255) / 256, 256, 0, stream>>>(MaxY, MinY, stats, x1m, 32);

    // --- kNN on x1_max (C=32) ---
    pack_kernel<32><<<dim3(NN / 64, BB), 256, 0, stream>>>(x1m, pkbuf);
    halfnorm_kernel<32><<<hn_grid, 256, 0, stream>>>(x1m, hng);
    knn_kernel<32><<<knn_grid, 256, 0, stream>>>(x1m, pkbuf, hng, idx2);

    // --- conv2: Cout=64, groups (x, idx1, 3) + (x1m, idx2, 32), w2 CIN=70 ---
    zero_kernel<<<1, 256, 0, stream>>>(stats, 128);
    precompute_kernel<64><<<dim3(NN / 64, BB), dim3(64, 4), 2 * 3 * 64 * 4, stream>>>(
        x, 3, w2, 70, 0, 3, G1, H, 1, 1);
    precompute_kernel<64><<<dim3(NN / 64, BB), dim3(64, 4), 2 * 32 * 64 * 4, stream>>>(
        x1m, 32, w2, 70, 6, 38, G2, H, 1, 0);
    conv_stats_kernel<64, 2><<<dim3(NN / 4, BB), dim3(64, 4), 0, stream>>>(
        G1, idx1, G2, idx2, H, stats, MaxY, MinY);
    finalize_kernel<<<1, 64, 0, stream>>>(g2, b2, stats, 64, invP);
    apply_kernel<<<(BB * 64 * NN + 255) / 256, 256, 0, stream>>>(MaxY, MinY, stats, x2m, 64);

    // --- convd1: Cout=64, group (x1m, idx2, 32), wd1 CIN=64 ---
    zero_kernel<<<1, 256, 0, stream>>>(stats, 128);
    precompute_kernel<64><<<dim3(NN / 64, BB), dim3(64, 4), 2 * 32 * 64 * 4, stream>>>(
        x1m, 32, wd1, 64, 0, 32, G1, H, 1, 1);
    conv_stats_kernel<64, 1><<<dim3(NN / 4, BB), dim3(64, 4), 0, stream>>>(
        G1, idx2, nullptr, nullptr, H, stats, MaxY, MinY);
    finalize_kernel<<<1, 64, 0, stream>>>(gd1, bd1, stats, 64, invP);
    apply_kernel<<<(BB * 64 * NN + 255) / 256, 256, 0, stream>>>(MaxY, MinY, stats, xd1, 64);

    // --- kNN on x2_max (C=64) ---
    pack_kernel<64><<<dim3(NN / 64, BB), 256, 0, stream>>>(x2m, pkbuf);
    halfnorm_kernel<64><<<hn_grid, 256, 0, stream>>>(x2m, hng);
    knn_kernel<64><<<knn_grid, 256, 0, stream>>>(x2m, pkbuf, hng, idx3);

    // --- convd2: Cout=64, group (x2m, idx3, 64), wd2 CIN=128 ---
    zero_kernel<<<1, 256, 0, stream>>>(stats, 128);
    precompute_kernel<64><<<dim3(NN / 64, BB), dim3(64, 4), 2 * 64 * 64 * 4, stream>>>(
        x2m, 64, wd2, 128, 0, 64, G1, H, 1, 1);
    conv_stats_kernel<64, 1><<<dim3(NN / 4, BB), dim3(64, 4), 0, stream>>>(
        G1, idx3, nullptr, nullptr, H, stats, MaxY, MinY);
    finalize_kernel<<<1, 64, 0, stream>>>(gd2, bd2, stats, 64, invP);
    apply_kernel<<<(BB * 64 * NN + 255) / 256, 256, 0, stream>>>(MaxY, MinY, stats, xd2, 64);

    // --- global mean + MLP head ---
    mean_kernel<<<1024, 256, 0, stream>>>(xd1, xd2, hsum);
    head_kernel<<<1, 128, 0, stream>>>(hsum, W2d, b2d, W3d, b3d, W4d, b4d, out);
}

// Round 7
// 1706.438 us; speedup vs baseline: 1.5619x; 1.0289x over previous
//
#include <hip/hip_runtime.h>

#define BB 8
#define NN 4096
#define KK 20
constexpr float EPSV = 1e-5f;
constexpr float SLOPE = 0.2f;

typedef __bf16 bfrag __attribute__((ext_vector_type(8)));
typedef float floatx4 __attribute__((ext_vector_type(4)));
typedef unsigned short us4 __attribute__((ext_vector_type(4)));
typedef unsigned short us8 __attribute__((ext_vector_type(8)));

__device__ __forceinline__ float lrelu(float v) { return v >= 0.f ? v : SLOPE * v; }

__device__ __forceinline__ unsigned short bf16rn(float f) {
    unsigned int u = __float_as_uint(f);
    return (unsigned short)((u + 0x7FFFu + ((u >> 16) & 1u)) >> 16);
}
__device__ __forceinline__ float bf16up(unsigned short h) {
    return __uint_as_float(((unsigned int)h) << 16);
}

// async global->LDS DMA, 16B per lane; lds dest must be wave-uniform base.
__device__ __forceinline__ void gl_lds16(const unsigned short* g, unsigned short* l) {
    __builtin_amdgcn_global_load_lds((const __attribute__((address_space(1))) void*)g,
                                     (__attribute__((address_space(3))) void*)l, 16, 0, 0);
}

__global__ void zero_kernel(float* p, int n) {
    int i = blockIdx.x * 256 + threadIdx.x;
    if (i < n) p[i] = 0.f;
}

// 0.5*||x_n||^2 per point (exact fp32). grid (NN/256, BB), block 256.
template<int C>
__global__ void halfnorm_kernel(const float* __restrict__ src, float* __restrict__ hng) {
    int n = blockIdx.x * 256 + threadIdx.x;
    int b = blockIdx.y;
    float s = 0.f;
    #pragma unroll
    for (int c = 0; c < C; c++) { float v = src[(b * C + c) * NN + n]; s += v * v; }
    hng[b * NN + n] = 0.5f * s;
}

// ---------------- one-shot bf16 hi/lo pack (C>=32) ----------------
// pk[(b*NN+m)*SK + k]: [0,C)=hi; [C,2C)=lo; [2C,2C+2)=hn fp32 bits; rest 0.
// MFMA fragments only read [0,2C) so the hn pad never enters the matmul.
template<int C>
__global__ void pack_kernel(const float* __restrict__ src, const float* __restrict__ hng,
                            unsigned short* __restrict__ pk) {
    constexpr int SK = 2 * C + 8;
    const int b = blockIdx.y;
    const int m0 = blockIdx.x * 64;
    const int tid = threadIdx.x;
    for (int i = tid; i < 64 * (C / 4); i += 256) {
        int m = i & 63;
        int c4 = (i >> 6) * 4;
        us4 hv, lv;
        #pragma unroll
        for (int j = 0; j < 4; j++) {
            float v = src[(b * C + c4 + j) * NN + m0 + m];
            unsigned short h = bf16rn(v);
            hv[j] = h;
            lv[j] = bf16rn(v - bf16up(h));
        }
        *(us4*)(&pk[(size_t)(b * NN + m0 + m) * SK + c4]) = hv;
        *(us4*)(&pk[(size_t)(b * NN + m0 + m) * SK + C + c4]) = lv;
    }
    if (tid < 64) {
        unsigned int ub = __float_as_uint(hng[b * NN + m0 + tid]);
        us8 z;
        #pragma unroll
        for (int j = 0; j < 8; j++) z[j] = 0;
        z[0] = (unsigned short)(ub & 0xFFFFu);
        z[1] = (unsigned short)(ub >> 16);
        *(us8*)(&pk[(size_t)(b * NN + m0 + tid) * SK + 2 * C]) = z;
    }
}

// C=3 B-pack: [h3 l3 l3 h3 | 0 x20 | hn fp32 | 0 x6] per point (SK=40).
// B fragments read k in [0,32) only; hn pad at [32,34) untouched by MFMA.
__global__ void pack3_kernel(const float* __restrict__ src, const float* __restrict__ hng,
                             unsigned short* __restrict__ pk) {
    const int b = blockIdx.y;
    const int m = blockIdx.x * 256 + threadIdx.x;
    us8 w0, w1;
    #pragma unroll
    for (int j = 0; j < 8; j++) { w0[j] = 0; w1[j] = 0; }
    unsigned short row[12];
    #pragma unroll
    for (int c = 0; c < 3; c++) {
        float v = src[(b * 3 + c) * NN + m];
        unsigned short h = bf16rn(v);
        unsigned short l = bf16rn(v - bf16up(h));
        row[c] = h; row[3 + c] = l; row[6 + c] = l; row[9 + c] = h;
    }
    #pragma unroll
    for (int j = 0; j < 8; j++) w0[j] = row[j];
    #pragma unroll
    for (int j = 0; j < 4; j++) w1[j] = row[8 + j];
    unsigned short* dst = pk + (size_t)(b * NN + m) * 40;
    us8 z;
    #pragma unroll
    for (int j = 0; j < 8; j++) z[j] = 0;
    unsigned int ub = __float_as_uint(hng[b * NN + m]);
    us8 zh = z;
    zh[0] = (unsigned short)(ub & 0xFFFFu);
    zh[1] = (unsigned short)(ub >> 16);
    *(us8*)(dst) = w0;
    *(us8*)(dst + 8) = w1;
    *(us8*)(dst + 16) = z;
    *(us8*)(dst + 24) = z;
    *(us8*)(dst + 32) = zh;
}

// ---------------- kNN via MFMA (bf16 hi/lo split, 4-term exact) ----------------
// Round-7: measured-305 geometry (64 q/block, exact running tau, pool + tid<64
// drain, XCD pinning) with the phase skeleton collapsed:
//  * double-buffered global_load_lds staging (async DMA, no VGPR round trip,
//    no commit phase, no LDS write traffic) issued at the top of Phase A;
//    the barrier's implicit vmcnt(0) completes it under ~600cy of MFMA cover.
//  * hn rides in the row pad of pk (staged by the same DMA; read from LDS).
//  * 2 barriers/chunk (was 3). LDS ~60KB (2 blocks/CU, grid-capped anyway).
template<int C>
__global__ __launch_bounds__(256) void knn_kernel(const float* __restrict__ src,
                                                  const unsigned short* __restrict__ pk,
                                                  int* __restrict__ idx) {
    constexpr int SK = (C == 3) ? 40 : (2 * C + 8);   // padded k-stride (shorts)
    constexpr int HNOFF = (C == 3) ? 32 : 2 * C;      // hn fp32 offset in row
    constexpr int UNITS = 8 * SK;                     // 16B units per 64-row chunk (mult of 64)
    constexpr int PF = (UNITS + 255) / 256;
    constexpr int KKN = (C == 3) ? 1 : (C / 32);
    __shared__ __attribute__((aligned(16))) unsigned short cpack[2 * 64 * SK];
    __shared__ float pv[64 * 65];
    __shared__ unsigned short pidx[64 * 66];
    __shared__ float tau[64];
    __shared__ int cnt[64];
    __shared__ unsigned short qls[(C == 3) ? 64 * 40 : 2];

    const int bid = blockIdx.x;
    const int b = bid & 7;               // batch -> XCD (wgid % 8 round-robin)
    const int q0 = (bid >> 3) * 64;
    const int tid = threadIdx.x;
    const int lane = tid & 63;
    const int wv = tid >> 6;
    const int wr = (wv >> 1) * 32;      // wave q-offset in [0,64)
    const int wc = (wv & 1) * 32;       // wave m-offset in [0,64)
    const int fl = lane & 15;
    const int fq = lane >> 4;

    float tv[20]; int ti[20];
    #pragma unroll
    for (int k = 0; k < 20; k++) { tv[k] = -3.4e38f; ti[k] = 0; }

    // ---- A fragments (registers, once) ----
    bfrag qah[KKN][2], qal[KKN][2];
    if (C == 3) {
        for (int i = tid; i < 64 * 20; i += 256) {
            int r = i / 20, k = 12 + i % 20;
            qls[r * 40 + k] = 0;
        }
        if (tid < 64) {
            #pragma unroll
            for (int c = 0; c < 3; c++) {
                float v = src[(b * 3 + c) * NN + q0 + tid];
                unsigned short h = bf16rn(v);
                unsigned short l = bf16rn(v - bf16up(h));
                // A-pack: [h3 l3 h3 l3 | 0...] pairs with B-pack [h3 l3 l3 h3]
                qls[tid * 40 + c] = h;  qls[tid * 40 + 3 + c] = l;
                qls[tid * 40 + 6 + c] = h;  qls[tid * 40 + 9 + c] = l;
            }
        }
    } else {
        #pragma unroll
        for (int r2 = 0; r2 < 2; r2++) {
            const unsigned short* qr = pk + (size_t)(b * NN + q0 + wr + r2 * 16 + fl) * SK + fq * 8;
            #pragma unroll
            for (int kk = 0; kk < KKN; kk++) {
                qah[kk][r2] = *(const bfrag*)(qr + kk * 32);
                qal[kk][r2] = *(const bfrag*)(qr + C + kk * 32);
            }
        }
    }

    // ---- prologue: async-stage chunk 0 into buffer 0 ----
    {
        const unsigned short* p0 = pk + (size_t)(b * NN) * SK;
        #pragma unroll
        for (int r = 0; r < PF; r++) {
            int u0 = r * 256 + wv * 64;          // wave-uniform base unit
            if (u0 < UNITS)
                gl_lds16(p0 + (size_t)(u0 + lane) * 8, cpack + (size_t)u0 * 8);
        }
    }
    if (tid < 64) { tau[tid] = -3.4e38f; cnt[tid] = 0; }
    __syncthreads();    // drains vmcnt: chunk 0 resident

    bfrag qa3[2];
    if (C == 3) {
        #pragma unroll
        for (int r2 = 0; r2 < 2; r2++)
            qa3[r2] = *(const bfrag*)(&qls[(wr + r2 * 16 + fl) * 40 + fq * 8]);
    }

    int buf = 0;
    for (int ch = 0; ch < 64; ch++) {
        unsigned short* cur = cpack + buf * (64 * SK);
        // ---- Phase A: issue async stage of ch+1; MFMA + filter on cur ----
        if (ch + 1 < 64) {
            unsigned short* nxt = cpack + (buf ^ 1) * (64 * SK);
            const unsigned short* pn = pk + (size_t)(b * NN + (ch + 1) * 64) * SK;
            #pragma unroll
            for (int r = 0; r < PF; r++) {
                int u0 = r * 256 + wv * 64;
                if (u0 < UNITS)
                    gl_lds16(pn + (size_t)(u0 + lane) * 8, nxt + (size_t)u0 * 8);
            }
        }

        floatx4 acc[2][2];
        #pragma unroll
        for (int r2 = 0; r2 < 2; r2++)
            #pragma unroll
            for (int c2 = 0; c2 < 2; c2++)
                acc[r2][c2] = (floatx4)(0.f);

        if (C == 3) {
            #pragma unroll
            for (int c2 = 0; c2 < 2; c2++) {
                bfrag bm = *(const bfrag*)(&cur[(wc + c2 * 16 + fl) * SK + fq * 8]);
                #pragma unroll
                for (int r2 = 0; r2 < 2; r2++)
                    acc[r2][c2] = __builtin_amdgcn_mfma_f32_16x16x32_bf16(qa3[r2], bm, acc[r2][c2], 0, 0, 0);
            }
        } else {
            #pragma unroll
            for (int kk = 0; kk < KKN; kk++) {
                const int kb = kk * 32 + fq * 8;
                bfrag bh[2], bl[2];
                #pragma unroll
                for (int c2 = 0; c2 < 2; c2++) {
                    bh[c2] = *(const bfrag*)(&cur[(wc + c2 * 16 + fl) * SK + kb]);
                    bl[c2] = *(const bfrag*)(&cur[(wc + c2 * 16 + fl) * SK + C + kb]);
                }
                #pragma unroll
                for (int r2 = 0; r2 < 2; r2++)
                    #pragma unroll
                    for (int c2 = 0; c2 < 2; c2++) {
                        acc[r2][c2] = __builtin_amdgcn_mfma_f32_16x16x32_bf16(qah[kk][r2], bh[c2], acc[r2][c2], 0, 0, 0);
                        acc[r2][c2] = __builtin_amdgcn_mfma_f32_16x16x32_bf16(qah[kk][r2], bl[c2], acc[r2][c2], 0, 0, 0);
                        acc[r2][c2] = __builtin_amdgcn_mfma_f32_16x16x32_bf16(qal[kk][r2], bh[c2], acc[r2][c2], 0, 0, 0);
                        acc[r2][c2] = __builtin_amdgcn_mfma_f32_16x16x32_bf16(qal[kk][r2], bl[c2], acc[r2][c2], 0, 0, 0);
                    }
            }
        }

        // ---- filter: C-layout col=lane&15 (m), row=fq*4+reg (q); exact tau;
        //      hn read from the staged row pad in LDS ----
        {
            const int m0 = ch * 64;
            float hvv[2];
            #pragma unroll
            for (int c2 = 0; c2 < 2; c2++)
                hvv[c2] = *(const float*)(&cur[(wc + c2 * 16 + fl) * SK + HNOFF]);
            #pragma unroll
            for (int r2 = 0; r2 < 2; r2++) {
                const int qb = wr + r2 * 16 + fq * 4;
                float4 t4 = *(const float4*)(&tau[qb]);
                float ta[4] = { t4.x, t4.y, t4.z, t4.w };
                #pragma unroll
                for (int c2 = 0; c2 < 2; c2++) {
                    const float hv = hvv[c2];
                    const int mm = m0 + wc + c2 * 16 + fl;
                    #pragma unroll
                    for (int reg = 0; reg < 4; reg++) {
                        float s = acc[r2][c2][reg] - hv;
                        if (s > ta[reg]) {
                            int q = qb + reg;
                            int p = atomicAdd(&cnt[q], 1);   // <= 64 per chunk: fits
                            pv[q * 65 + p] = s;
                            pidx[q * 66 + p] = (unsigned short)mm;
                        }
                    }
                }
            }
        }
        __syncthreads();   // B1: pool complete; vmcnt(0) -> next chunk resident

        // ---- Phase B: drain (tid<64, lane-parallel over q); exact top-20 + tau ----
        if (tid < 64) {
            int n = cnt[tid];
            for (int t = 0; t < n; t++) {
                float v = pv[tid * 65 + t];
                if (v > tv[0]) {
                    tv[0] = v; ti[0] = (int)pidx[tid * 66 + t];
                    #pragma unroll
                    for (int j = 0; j < 19; j++) {
                        if (tv[j] > tv[j + 1]) {
                            float a = tv[j]; tv[j] = tv[j + 1]; tv[j + 1] = a;
                            int bi = ti[j]; ti[j] = ti[j + 1]; ti[j + 1] = bi;
                        }
                    }
                }
            }
            cnt[tid] = 0;
            tau[tid] = tv[0];
        }
        __syncthreads();   // B2: tau/cnt ready
        buf ^= 1;
    }

    if (tid < 64) {
        #pragma unroll
        for (int k = 0; k < 20; k++)
            idx[(b * NN + q0 + tid) * KK + k] = ti[k];   // order irrelevant downstream
    }
}

// ---------------- conv precompute: G = Wd*src, H = (Wc-Wd)*src ----------------
template<int COUT>
__global__ void precompute_kernel(const float* __restrict__ src, int C,
                                  const float* __restrict__ w, int CIN, int wd_off, int wc_off,
                                  float* __restrict__ G, float* __restrict__ H,
                                  int initG, int initH) {
    constexpr int MY = 256 / COUT;
    extern __shared__ float lds[];
    float* wd = lds;
    float* wc = lds + C * COUT;
    const int b = blockIdx.y;
    const int tid = threadIdx.y * COUT + threadIdx.x;
    for (int i = tid; i < C * COUT; i += 256) {
        int c = i / COUT, o = i % COUT;
        float a  = w[o * CIN + wd_off + c];
        float cc = w[o * CIN + wc_off + c];
        wd[i] = a;
        wc[i] = cc - a;
    }
    __syncthreads();
    const int o = threadIdx.x;
    for (int it = 0; it < COUT / 4; it++) {
        int m = blockIdx.x * 64 + it * MY + threadIdx.y;
        float g = 0.f, h = 0.f;
        for (int c = 0; c < C; c++) {
            float s = src[(b * C + c) * NN + m];
            g += wd[c * COUT + o] * s;
            h += wc[c * COUT + o] * s;
        }
        int gi = (b * NN + m) * COUT + o;
        if (initG) G[gi] = g; else G[gi] += g;
        if (initH) H[gi] = h; else H[gi] += h;
    }
}

// ---------------- conv stats + per-(b,n,o) min/max over k ----------------
template<int COUT, int GROUPS>
__global__ void conv_stats_kernel(const float* __restrict__ G1, const int* __restrict__ idx1,
                                  const float* __restrict__ G2, const int* __restrict__ idx2,
                                  const float* __restrict__ H, float* __restrict__ stats,
                                  float* __restrict__ MaxY, float* __restrict__ MinY) {
    constexpr int NY = 256 / COUT;
    const int b = blockIdx.y;
    const int o = threadIdx.x;
    const int n = blockIdx.x * NY + threadIdx.y;
    const int base = b * NN + n;
    const float h = H[base * COUT + o];
    float s1 = 0.f, s2 = 0.f;
    float gx = -3.4e38f, gn = 3.4e38f;
    #pragma unroll
    for (int k = 0; k < KK; k++) {
        int i1 = idx1[base * KK + k];
        float g = G1[(b * NN + i1) * COUT + o];
        if (GROUPS == 2) {
            int i2 = idx2[base * KK + k];
            g += G2[(b * NN + i2) * COUT + o];
        }
        float y = g + h;
        s1 += y;
        s2 += y * y;
        gx = fmaxf(gx, g);
        gn = fminf(gn, g);
    }
    MaxY[base * COUT + o] = gx + h;
    MinY[base * COUT + o] = gn + h;

    __shared__ float ls[2 * COUT];
    if (threadIdx.y == 0) { ls[o] = 0.f; ls[COUT + o] = 0.f; }
    __syncthreads();
    atomicAdd(&ls[o], s1);
    atomicAdd(&ls[COUT + o], s2);
    __syncthreads();
    if (threadIdx.y == 0) {
        atomicAdd(&stats[o], ls[o]);
        atomicAdd(&stats[64 + o], ls[COUT + o]);
    }
}

__global__ void finalize_kernel(const float* __restrict__ g, const float* __restrict__ bb,
                                float* __restrict__ stats, int cout, float invP) {
    int o = threadIdx.x;
    if (o >= cout) return;
    float mu  = stats[o] * invP;
    float var = stats[64 + o] * invP - mu * mu;
    float sc  = g[o] * rsqrtf(var + EPSV);
    stats[128 + o] = sc;
    stats[192 + o] = bb[o] - mu * sc;
}

__global__ void apply_kernel(const float* __restrict__ MaxY, const float* __restrict__ MinY,
                             const float* __restrict__ stats, float* __restrict__ out, int cout) {
    int e = blockIdx.x * 256 + threadIdx.x;
    int total = BB * cout * NN;
    if (e >= total) return;
    int n = e & (NN - 1);
    int o = (e >> 12) % cout;
    int b = e / (NN * cout);
    float sc = stats[128 + o], sh = stats[192 + o];
    int si = (b * NN + n) * cout + o;
    float v = (sc >= 0.f) ? MaxY[si] : MinY[si];
    out[e] = lrelu(sc * v + sh);
}

__global__ void mean_kernel(const float* __restrict__ xd1, const float* __restrict__ xd2,
                            float* __restrict__ hsum) {
    __shared__ float bins[128];
    const int tid = threadIdx.x;
    if (tid < 128) bins[tid] = 0.f;
    __syncthreads();
    const int half = BB * 64 * NN;
    const int stride = gridDim.x * 256;
    for (int e = blockIdx.x * 256 + tid; e < half; e += stride)
        atomicAdd(&bins[e & 127], xd1[e]);
    for (int e = blockIdx.x * 256 + tid; e < half; e += stride)
        atomicAdd(&bins[e & 127], xd2[e]);
    __syncthreads();
    if (tid < 128) atomicAdd(&hsum[tid], bins[tid]);
}

__global__ void head_kernel(const float* __restrict__ hsum,
                            const float* __restrict__ W2d, const float* __restrict__ b2d,
                            const float* __restrict__ W3d, const float* __restrict__ b3d,
                            const float* __restrict__ W4d, const float* __restrict__ b4d,
                            float* __restrict__ out) {
    __shared__ float h[128], t1[128], t2[64];
    const int t = threadIdx.x;
    h[t] = hsum[t] * (1.f / 32768.f);
    __syncthreads();
    float a = b2d[t];
    for (int j = 0; j < 128; j++) a += W2d[t * 128 + j] * h[j];
    t1[t] = lrelu(a);
    __syncthreads();
    if (t < 64) {
        float a2 = b3d[t];
        for (int j = 0; j < 128; j++) a2 += W3d[t * 128 + j] * t1[j];
        t2[t] = lrelu(a2);
    }
    __syncthreads();
    if (t < 11) {
        float a3 = b4d[t];
        for (int j = 0; j < 64; j++) a3 += W4d[t * 64 + j] * t2[j];
        out[t] = lrelu(a3);
    }
}

extern "C" void kernel_launch(void* const* d_in, const int* in_sizes, int n_in,
                              void* d_out, int out_size, void* d_ws, size_t ws_size,
                              hipStream_t stream) {
    const float* x   = (const float*)d_in[0];
    const float* w1  = (const float*)d_in[1];
    const float* g1  = (const float*)d_in[2];
    const float* b1  = (const float*)d_in[3];
    const float* w2  = (const float*)d_in[4];
    const float* g2  = (const float*)d_in[5];
    const float* b2  = (const float*)d_in[6];
    const float* wd1 = (const float*)d_in[7];
    const float* gd1 = (const float*)d_in[8];
    const float* bd1 = (const float*)d_in[9];
    const float* wd2 = (const float*)d_in[10];
    const float* gd2 = (const float*)d_in[11];
    const float* bd2 = (const float*)d_in[12];
    const float* W2d = (const float*)d_in[13];
    const float* b2d = (const float*)d_in[14];
    const float* W3d = (const float*)d_in[15];
    const float* b3d = (const float*)d_in[16];
    const float* W4d = (const float*)d_in[17];
    const float* b4d = (const float*)d_in[18];
    float* out = (float*)d_out;

    char* ws = (char*)d_ws;
    size_t off = 0;
    auto alloc = [&](size_t bytes) { char* p = ws + off; off += (bytes + 255) & ~size_t(255); return p; };
    int*   idx1  = (int*)  alloc(BB * NN * KK * 4);
    int*   idx2  = (int*)  alloc(BB * NN * KK * 4);
    int*   idx3  = (int*)  alloc(BB * NN * KK * 4);
    float* x1m   = (float*)alloc(BB * 32 * NN * 4);
    float* x2m   = (float*)alloc(BB * 64 * NN * 4);
    float* xd1   = (float*)alloc(BB * 64 * NN * 4);
    float* xd2   = (float*)alloc(BB * 64 * NN * 4);
    float* G1    = (float*)alloc((size_t)BB * NN * 64 * 4);
    float* G2    = (float*)alloc((size_t)BB * NN * 64 * 4);
    float* H     = (float*)alloc((size_t)BB * NN * 64 * 4);
    float* MaxY  = (float*)alloc((size_t)BB * NN * 64 * 4);
    float* MinY  = (float*)alloc((size_t)BB * NN * 64 * 4);
    float* stats = (float*)alloc(256 * 4);
    float* hsum  = (float*)alloc(128 * 4);
    float* hng   = (float*)alloc(BB * NN * 4);

    // pk scratch reuses MaxY (+ start of MinY for C=64); dead at every kNN site.
    unsigned short* pkbuf = (unsigned short*)MaxY;

    const float invP = 1.f / (float)(BB * NN * KK);
    const dim3 knn_grid(NN / 64 * BB);     // 1D: b = id & 7 (XCD pinning), q0 = (id>>3)*64
    const dim3 hn_grid(NN / 256, BB);

    zero_kernel<<<1, 256, 0, stream>>>(hsum, 128);

    // --- kNN on x (C=3) ---
    halfnorm_kernel<3><<<hn_grid, 256, 0, stream>>>(x, hng);
    pack3_kernel<<<dim3(NN / 256, BB), 256, 0, stream>>>(x, hng, pkbuf);
    knn_kernel<3><<<knn_grid, 256, 0, stream>>>(x, pkbuf, idx1);

    // --- conv1: Cout=32, group (x, idx1, C=3), w1 CIN=6 ---
    zero_kernel<<<1, 256, 0, stream>>>(stats, 128);
    precompute_kernel<32><<<dim3(NN / 64, BB), dim3(32, 8), 2 * 3 * 32 * 4, stream>>>(
        x, 3, w1, 6, 0, 3, G1, H, 1, 1);
    conv_stats_kernel<32, 1><<<dim3(NN / 8, BB), dim3(32, 8), 0, stream>>>(
        G1, idx1, nullptr, nullptr, H, stats, MaxY, MinY);
    finalize_kernel<<<1, 64, 0, stream>>>(g1, b1, stats, 32, invP);
    apply_kernel<<<(BB * 32 * NN + 255) / 256, 256, 0, stream>>>(MaxY, MinY, stats, x1m, 32);

    // --- kNN on x1_max (C=32) ---
    halfnorm_kernel<32><<<hn_grid, 256, 0, stream>>>(x1m, hng);
    pack_kernel<32><<<dim3(NN / 64, BB), 256, 0, stream>>>(x1m, hng, pkbuf);
    knn_kernel<32><<<knn_grid, 256, 0, stream>>>(x1m, pkbuf, idx2);

    // --- conv2: Cout=64, groups (x, idx1, 3) + (x1m, idx2, 32), w2 CIN=70 ---
    zero_kernel<<<1, 256, 0, stream>>>(stats, 128);
    precompute_kernel<64><<<dim3(NN / 64, BB), dim3(64, 4), 2 * 3 * 64 * 4, stream>>>(
        x, 3, w2, 70, 0, 3, G1, H, 1, 1);
    precompute_kernel<64><<<dim3(NN / 64, BB), dim3(64, 4), 2 * 32 * 64 * 4, stream>>>(
        x1m, 32, w2, 70, 6, 38, G2, H, 1, 0);
    conv_stats_kernel<64, 2><<<dim3(NN / 4, BB), dim3(64, 4), 0, stream>>>(
        G1, idx1, G2, idx2, H, stats, MaxY, MinY);
    finalize_kernel<<<1, 64, 0, stream>>>(g2, b2, stats, 64, invP);
    apply_kernel<<<(BB * 64 * NN + 255) / 256, 256, 0, stream>>>(MaxY, MinY, stats, x2m, 64);

    // --- convd1: Cout=64, group (x1m, idx2, 32), wd1 CIN=64 ---
    zero_kernel<<<1, 256, 0, stream>>>(stats, 128);
    precompute_kernel<64><<<dim3(NN / 64, BB), dim3(64, 4), 2 * 32 * 64 * 4, stream>>>(
        x1m, 32, wd1, 64, 0, 32, G1, H, 1, 1);
    conv_stats_kernel<64, 1><<<dim3(NN / 4, BB), dim3(64, 4), 0, stream>>>(
        G1, idx2, nullptr, nullptr, H, stats, MaxY, MinY);
    finalize_kernel<<<1, 64, 0, stream>>>(gd1, bd1, stats, 64, invP);
    apply_kernel<<<(BB * 64 * NN + 255) / 256, 256, 0, stream>>>(MaxY, MinY, stats, xd1, 64);

    // --- kNN on x2_max (C=64) ---
    halfnorm_kernel<64><<<hn_grid, 256, 0, stream>>>(x2m, hng);
    pack_kernel<64><<<dim3(NN / 64, BB), 256, 0, stream>>>(x2m, hng, pkbuf);
    knn_kernel<64><<<knn_grid, 256, 0, stream>>>(x2m, pkbuf, idx3);

    // --- convd2: Cout=64, group (x2m, idx3, 64), wd2 CIN=128 ---
    zero_kernel<<<1, 256, 0, stream>>>(stats, 128);
    precompute_kernel<64><<<dim3(NN / 64, BB), dim3(64, 4), 2 * 64 * 64 * 4, stream>>>(
        x2m, 64, wd2, 128, 0, 64, G1, H, 1, 1);
    conv_stats_kernel<64, 1><<<dim3(NN / 4, BB), dim3(64, 4), 0, stream>>>(
        G1, idx3, nullptr, nullptr, H, stats, MaxY, MinY);
    finalize_kernel<<<1, 64, 0, stream>>>(gd2, bd2, stats, 64, invP);
    apply_kernel<<<(BB * 64 * NN + 255) / 256, 256, 0, stream>>>(MaxY, MinY, stats, xd2, 64);

    // --- global mean + MLP head ---
    mean_kernel<<<1024, 256, 0, stream>>>(xd1, xd2, hsum);
    head_kernel<<<1, 128, 0, stream>>>(hsum, W2d, b2d, W3d, b3d, W4d, b4d, out);
}